// Round 1
// 2591.264 us; speedup vs baseline: 4.6034x; 4.6034x over previous
//
#include <hip/hip_runtime.h>
#include <hip/hip_bf16.h>
#include <cmath>

typedef __bf16 bf16_t;
typedef __bf16 bf16x4 __attribute__((ext_vector_type(4)));
typedef __bf16 bf16x8 __attribute__((ext_vector_type(8)));
typedef float f32x4 __attribute__((ext_vector_type(4)));

typedef const __attribute__((address_space(1))) void gv_t;
typedef __attribute__((address_space(3))) void sv_t;

#define GLDS16(g, l) __builtin_amdgcn_global_load_lds((gv_t*)(g), (sv_t*)(l), 16, 0, 0)

// ---------------- GEMM: C = A @ B^T (+bias)(+epilogue) ----------------
// A: [4096, K] bf16 row-major ; B: [N, K] bf16 row-major (weights [out,in])
// bias: f32. EPI: 0 = store f32, no bias ; 1 = +bias, store f32 ;
//      2 = +bias, Cf[row*1024+col] += v (residual, N==1024) ;
//      3 = +bias, gelu, store bf16 ; 4 = +bias, store bf16
template <int EPI>
__global__ __launch_bounds__(256, 2) void gemm128(
    const bf16_t* __restrict__ A, const bf16_t* __restrict__ B,
    const float* __restrict__ bias, float* __restrict__ Cf,
    bf16_t* __restrict__ Cb, int N, int K)
{
    __shared__ __align__(16) bf16_t As[128 * 32];
    __shared__ __align__(16) bf16_t Bs[128 * 32];
    const int tid = threadIdx.x;
    const int bm = blockIdx.x, bn = blockIdx.y;
    const int wave = tid >> 6, lane = tid & 63;
    const int wr = (wave >> 1) << 6, wc = (wave & 1) << 6;
    const int lr = lane & 15, kq = (lane >> 4) << 3;

    f32x4 acc[4][4] = {};

    const bf16_t* gA = A + (size_t)(bm * 128 + (tid >> 2)) * K + (tid & 3) * 8;
    const bf16_t* gB = B + (size_t)(bn * 128 + (tid >> 2)) * K + (tid & 3) * 8;
    const bf16_t* gA2 = gA + (size_t)64 * K;
    const bf16_t* gB2 = gB + (size_t)64 * K;
    bf16_t* lA = As + tid * 8;
    bf16_t* lB = Bs + tid * 8;

    for (int k0 = 0; k0 < K; k0 += 32) {
        __syncthreads();
        GLDS16(gA + k0, lA);
        GLDS16(gA2 + k0, lA + 2048);
        GLDS16(gB + k0, lB);
        GLDS16(gB2 + k0, lB + 2048);
        __syncthreads();
        bf16x8 af[4], bfr[4];
#pragma unroll
        for (int i = 0; i < 4; i++)
            af[i] = *(const bf16x8*)(As + (wr + i * 16 + lr) * 32 + kq);
#pragma unroll
        for (int j = 0; j < 4; j++)
            bfr[j] = *(const bf16x8*)(Bs + (wc + j * 16 + lr) * 32 + kq);
#pragma unroll
        for (int i = 0; i < 4; i++)
#pragma unroll
            for (int j = 0; j < 4; j++)
                acc[i][j] = __builtin_amdgcn_mfma_f32_16x16x32_bf16(af[i], bfr[j], acc[i][j], 0, 0, 0);
    }

    const int row0 = bm * 128 + wr + ((lane >> 4) << 2);
    const int col0 = bn * 128 + wc + lr;
#pragma unroll
    for (int j = 0; j < 4; j++) {
        const int col = col0 + j * 16;
        float bv = 0.f;
        if constexpr (EPI != 0) bv = bias[col];
#pragma unroll
        for (int i = 0; i < 4; i++) {
#pragma unroll
            for (int r = 0; r < 4; r++) {
                const int row = row0 + i * 16 + r;
                float v = acc[i][j][r] + bv;
                if constexpr (EPI == 0 || EPI == 1) {
                    Cf[(size_t)row * N + col] = v;
                } else if constexpr (EPI == 2) {
                    Cf[(size_t)row * 1024 + col] += v;
                } else if constexpr (EPI == 3) {
                    float g = 0.5f * v * (1.f + tanhf(0.7978845608f * (v + 0.044715f * v * v * v)));
                    Cb[(size_t)row * N + col] = (bf16_t)g;
                } else {
                    Cb[(size_t)row * N + col] = (bf16_t)v;
                }
            }
        }
    }
}

// ---------------- per-layer weight convert f32 -> bf16 (4 tensors fused) ----------------
__global__ __launch_bounds__(256) void convw_k(
    const float* __restrict__ q, const float* __restrict__ p,
    const float* __restrict__ f1, const float* __restrict__ f2,
    bf16_t* __restrict__ oq, bf16_t* __restrict__ op,
    bf16_t* __restrict__ of1, bf16_t* __restrict__ of2)
{
    int idx = blockIdx.x * 256 + threadIdx.x;   // in float4 units; 3145728 total
    const float* src; bf16_t* dst; int off;
    if (idx < 786432)       { src = q;  dst = oq;  off = idx; }
    else if (idx < 1048576) { src = p;  dst = op;  off = idx - 786432; }
    else if (idx < 2097152) { src = f1; dst = of1; off = idx - 1048576; }
    else                    { src = f2; dst = of2; off = idx - 2097152; }
    float4 v = ((const float4*)src)[off];
    bf16x4 o; o[0] = (bf16_t)v.x; o[1] = (bf16_t)v.y; o[2] = (bf16_t)v.z; o[3] = (bf16_t)v.w;
    *(bf16x4*)(dst + (size_t)off * 4) = o;
}

// ---------------- generic f32 -> bf16 convert ----------------
__global__ __launch_bounds__(256) void cvt_k(const float* __restrict__ in, bf16_t* __restrict__ out)
{
    int idx = blockIdx.x * 256 + threadIdx.x;   // float4 units
    float4 v = ((const float4*)in)[idx];
    bf16x4 o; o[0] = (bf16_t)v.x; o[1] = (bf16_t)v.y; o[2] = (bf16_t)v.z; o[3] = (bf16_t)v.w;
    *(bf16x4*)(out + (size_t)idx * 4) = o;
}

// ---------------- SpatialMerger patch gather ----------------
__global__ __launch_bounds__(256) void patches_k(const float* __restrict__ x, bf16_t* __restrict__ out)
{
    int idx = blockIdx.x * 256 + threadIdx.x;  // 262144 total
    int cc = idx & 63, l = (idx >> 6) & 1023, n = idx >> 16;
    int c = cc >> 2, kh = (cc >> 1) & 1, kw = cc & 1;
    int hf = l >> 5, wf = l & 31;
    out[idx] = (bf16_t)x[(((n * 16 + c) * 64) + hf * 2 + kh) * 64 + wf * 2 + kw];
}

// ---------------- RMSNorm: tok f32 [4096,1024] -> bf16 ----------------
__global__ __launch_bounds__(256) void rmsnorm_k(const float* __restrict__ tok, bf16_t* __restrict__ out)
{
    int row = blockIdx.x, tid = threadIdx.x;
    float4 xv = ((const float4*)(tok + (size_t)row * 1024))[tid];
    float s = xv.x * xv.x + xv.y * xv.y + xv.z * xv.z + xv.w * xv.w;
#pragma unroll
    for (int off = 32; off > 0; off >>= 1) s += __shfl_down(s, off, 64);
    __shared__ float ws4[4];
    if ((tid & 63) == 0) ws4[tid >> 6] = s;
    __syncthreads();
    float sc = rsqrtf((ws4[0] + ws4[1] + ws4[2] + ws4[3]) * (1.f / 1024.f) + 1e-6f);
    bf16_t* o = out + (size_t)row * 1024 + tid * 4;
    bf16x4 ov;
    ov[0] = (bf16_t)(xv.x * sc); ov[1] = (bf16_t)(xv.y * sc);
    ov[2] = (bf16_t)(xv.z * sc); ov[3] = (bf16_t)(xv.w * sc);
    *(bf16x4*)o = ov;
}

// ---------------- 2D RoPE in-place on q,k inside qkv bf16 [4096,3072] ----------------
__global__ __launch_bounds__(256) void rope_k(bf16_t* __restrict__ qkv)
{
    int idx = blockIdx.x * 256 + threadIdx.x;  // 2097152 total
    int j = idx & 31, h = (idx >> 5) & 15, t = (idx >> 9) & 1023, n = idx >> 19;
    int b = j >> 4, jj = j & 15;
    float pos = (float)(b ? (t & 31) : (t >> 5));       // pos_w = t%32 ; pos_h = t/32
    float ang = pos * exp2f(-13.287712379549449f * (float)jj * (1.f / 16.f));  // 10000^(-jj/16)
    float sn, cs;
    sincosf(ang, &sn, &cs);
    bf16_t* qp = qkv + (size_t)(n * 1024 + t) * 3072 + h * 64 + b * 32 + jj;
    float q0 = (float)qp[0], q1 = (float)qp[16];
    qp[0]  = (bf16_t)(q0 * cs - q1 * sn);
    qp[16] = (bf16_t)(q1 * cs + q0 * sn);
    bf16_t* kp = qp + 1024;
    float k0 = (float)kp[0], k1 = (float)kp[16];
    kp[0]  = (bf16_t)(k0 * cs - k1 * sn);
    kp[16] = (bf16_t)(k1 * cs + k0 * sn);
}

// ---------------- V transpose: qkv v-section [n,t][h*64+d] -> vt [n,h,d][t] ----------------
__global__ __launch_bounds__(256) void vtrans_k(const bf16_t* __restrict__ qkv, bf16_t* __restrict__ vt)
{
    __shared__ bf16_t tile[64][72];   // 72*2=144 B rows, 16-B aligned
    const int tid = threadIdx.x, b = blockIdx.x;     // 1024 = n(4)*h(16)*tt(16)
    const int tt = b & 15, h = (b >> 4) & 15, n = b >> 8;
#pragma unroll
    for (int rr = 0; rr < 2; rr++) {
        int idx = rr * 256 + tid;
        int tr = idx >> 3, dc = (idx & 7) * 8;
        bf16x8 v = *(const bf16x8*)(qkv + (size_t)(n * 1024 + tt * 64 + tr) * 3072 + 2048 + h * 64 + dc);
        *(bf16x8*)&tile[tr][dc] = v;
    }
    __syncthreads();
#pragma unroll
    for (int rr = 0; rr < 2; rr++) {
        int idx = rr * 256 + tid;
        int d = idx >> 3, tc = (idx & 7) * 8;
        bf16x8 ov;
#pragma unroll
        for (int e = 0; e < 8; e++) ov[e] = tile[tc + e][d];
        *(bf16x8*)(vt + (size_t)((n * 16 + h) * 64 + d) * 1024 + tt * 64 + tc) = ov;
    }
}

// ---------------- MFMA flash attention ----------------
// grid 512 = n(4) * h(16) * qb(8). block = 4 waves; wave handles 32 q-rows.
// S^T = K@Q^T via mfma (row=s, col=t) so the key-reduce is in-lane + 2 shfl_xor.
// K,V staged via global_load_lds w/ granule-XOR swizzle (conflict-free ds_read_b128).
// V consumed from pre-transposed vt so PV is the plain A@B^T pattern.
__global__ __launch_bounds__(256, 2) void attn_mfma(
    const bf16_t* __restrict__ qkv, const bf16_t* __restrict__ vt, bf16_t* __restrict__ obuf)
{
    __shared__ __align__(16) bf16_t Ks[64 * 64];     // [s][d], swizzled
    __shared__ __align__(16) bf16_t Vs[64 * 64];     // [d][s], swizzled
    __shared__ __align__(16) bf16_t Ps[4][32 * 64];  // per-wave [t][s], swizzled

    const int tid = threadIdx.x, wave = tid >> 6, lane = tid & 63;
    const int lr = lane & 15, g = lane >> 4;
    const int blk = blockIdx.x;
    const int qb = blk & 7, h = (blk >> 3) & 15, n = blk >> 7;
    const int t0 = qb * 128 + wave * 32;             // wave's first q row (within head)

    // ---- Q fragments (B-operand layout), pre-scaled by 1/sqrt(64)=0.125 (exact in bf16)
    bf16x8 bq[2][2];
#pragma unroll
    for (int j = 0; j < 2; j++)
#pragma unroll
        for (int kk = 0; kk < 2; kk++) {
            bf16x8 v = *(const bf16x8*)(qkv + (size_t)(n * 1024 + t0 + j * 16 + lr) * 3072 + h * 64 + kk * 32 + g * 8);
#pragma unroll
            for (int e = 0; e < 8; e++) v[e] = (bf16_t)((float)v[e] * 0.125f);
            bq[j][kk] = v;
        }

    f32x4 o[2][4] = {};
    float m[2] = {-1e30f, -1e30f}, l[2] = {0.f, 0.f};

    // staging: dest granule idx = rr*256+tid -> row = tid>>3 + rr*32, phys col-granule = tid&7
    const int sr = tid >> 3, pcb = tid & 7;
    const int scb = (pcb ^ (sr & 7)) * 8;            // swizzled source column (elements)
    const bf16_t* ksrc = qkv + (size_t)(n * 1024 + sr) * 3072 + 1024 + h * 64 + scb;
    const bf16_t* vsrc = vt + (size_t)((n * 16 + h) * 64 + sr) * 1024 + scb;
    bf16_t* kdst = Ks + tid * 8;
    bf16_t* vdst = Vs + tid * 8;

    for (int s0 = 0; s0 < 1024; s0 += 64) {
        __syncthreads();
        GLDS16(ksrc + (size_t)s0 * 3072, kdst);
        GLDS16(ksrc + (size_t)(s0 + 32) * 3072, kdst + 2048);
        GLDS16(vsrc + s0, vdst);
        GLDS16(vsrc + s0 + (size_t)32 * 1024, vdst + 2048);
        __syncthreads();

        // ---- S^T = K @ Q^T  (row=s: 4 blocks, col=t: 2 blocks)
        f32x4 st[4][2] = {};
#pragma unroll
        for (int kk = 0; kk < 2; kk++) {
            bf16x8 ak[4];
#pragma unroll
            for (int i = 0; i < 4; i++)
                ak[i] = *(const bf16x8*)((const char*)Ks + (i * 16 + lr) * 128 + (((kk * 4 + g) ^ (lr & 7)) * 16));
#pragma unroll
            for (int i = 0; i < 4; i++)
#pragma unroll
                for (int j = 0; j < 2; j++)
                    st[i][j] = __builtin_amdgcn_mfma_f32_16x16x32_bf16(ak[i], bq[j][kk], st[i][j], 0, 0, 0);
        }

        // ---- online softmax per t-column; write P (bf16) to per-wave LDS as [t][s]
        float al2[2];
#pragma unroll
        for (int j = 0; j < 2; j++) {
            float rm = st[0][j][0];
#pragma unroll
            for (int i = 0; i < 4; i++)
#pragma unroll
                for (int r = 0; r < 4; r++) rm = fmaxf(rm, st[i][j][r]);
            rm = fmaxf(rm, __shfl_xor(rm, 16, 64));
            rm = fmaxf(rm, __shfl_xor(rm, 32, 64));
            float mn = fmaxf(m[j], rm);
            float al = __expf(m[j] - mn);
            m[j] = mn; al2[j] = al;
            float ps = 0.f;
#pragma unroll
            for (int i = 0; i < 4; i++) {
                bf16x4 pk;
#pragma unroll
                for (int r = 0; r < 4; r++) {
                    float p = __expf(st[i][j][r] - mn);
                    bf16_t pb = (bf16_t)p;
                    pk[r] = pb;
                    ps += (float)pb;      // l consistent with the bf16 P actually used
                }
                *(bf16x4*)((char*)&Ps[wave][0] + (j * 16 + lr) * 128 +
                           (((i * 2 + (g >> 1)) ^ (lr & 7)) * 16) + (g & 1) * 8) = pk;
            }
            ps += __shfl_xor(ps, 16, 64);
            ps += __shfl_xor(ps, 32, 64);
            l[j] = l[j] * al + ps;
        }

        // ---- rescale O by alpha (redistribute S^T-layout alpha -> O-row layout via shfl)
#pragma unroll
        for (int ti = 0; ti < 2; ti++)
#pragma unroll
            for (int r = 0; r < 4; r++) {
                float av = __shfl(al2[ti], g * 4 + r, 64);
#pragma unroll
                for (int dj = 0; dj < 4; dj++) o[ti][dj][r] *= av;
            }

        // ---- O += P @ V^T^T  (A=P rows t, B=V^T rows d)
#pragma unroll
        for (int kk = 0; kk < 2; kk++) {
            bf16x8 ap[2], bv[4];
#pragma unroll
            for (int ti = 0; ti < 2; ti++)
                ap[ti] = *(const bf16x8*)((const char*)&Ps[wave][0] + (ti * 16 + lr) * 128 +
                                          (((kk * 4 + g) ^ (lr & 7)) * 16));
#pragma unroll
            for (int dj = 0; dj < 4; dj++)
                bv[dj] = *(const bf16x8*)((const char*)Vs + (dj * 16 + lr) * 128 +
                                          (((kk * 4 + g) ^ (lr & 7)) * 16));
#pragma unroll
            for (int ti = 0; ti < 2; ti++)
#pragma unroll
                for (int dj = 0; dj < 4; dj++)
                    o[ti][dj] = __builtin_amdgcn_mfma_f32_16x16x32_bf16(ap[ti], bv[dj], o[ti][dj], 0, 0, 0);
        }
    }

    // ---- epilogue: O /= l, store bf16
#pragma unroll
    for (int ti = 0; ti < 2; ti++)
#pragma unroll
        for (int r = 0; r < 4; r++) {
            float lv = __shfl(l[ti], g * 4 + r, 64);
            float inv = 1.f / lv;
            const int trow = n * 1024 + qb * 128 + wave * 32 + ti * 16 + g * 4 + r;
#pragma unroll
            for (int dj = 0; dj < 4; dj++)
                obuf[(size_t)trow * 1024 + h * 64 + dj * 16 + lr] = (bf16_t)(o[ti][dj][r] * inv);
        }
}

// ---------------- final rmsnorm scale per token ----------------
__global__ __launch_bounds__(256) void rmsscale_k(const float* __restrict__ tok, float* __restrict__ scale)
{
    int row = blockIdx.x, tid = threadIdx.x;
    float4 xv = ((const float4*)(tok + (size_t)row * 1024))[tid];
    float s = xv.x * xv.x + xv.y * xv.y + xv.z * xv.z + xv.w * xv.w;
#pragma unroll
    for (int off = 32; off > 0; off >>= 1) s += __shfl_down(s, off, 64);
    __shared__ float ws4[4];
    if ((tid & 63) == 0) ws4[tid >> 6] = s;
    __syncthreads();
    if (tid == 0)
        scale[row] = rsqrtf((ws4[0] + ws4[1] + ws4[2] + ws4[3]) * (1.f / 1024.f) + 1e-6f);
}

// ---------------- scale + transpose: out f32 [n][d][t] = tok[n][t][d]*scale[n,t] ----------------
__global__ __launch_bounds__(256) void transpose_out_k(const float* __restrict__ tok,
                                                       const float* __restrict__ scale,
                                                       float* __restrict__ out)
{
    __shared__ float tile[64][65];
    const int tid = threadIdx.x;
    const int tt = blockIdx.x * 64, dd = blockIdx.y * 64, n = blockIdx.z;
#pragma unroll
    for (int rb = 0; rb < 4; rb++) {
        int tl = rb * 16 + (tid >> 4);
        int cl = (tid & 15) * 4;
        float4 v = *(const float4*)(tok + (size_t)(n * 1024 + tt + tl) * 1024 + dd + cl);
        float sc = scale[n * 1024 + tt + tl];
        tile[cl + 0][tl] = v.x * sc;
        tile[cl + 1][tl] = v.y * sc;
        tile[cl + 2][tl] = v.z * sc;
        tile[cl + 3][tl] = v.w * sc;
    }
    __syncthreads();
#pragma unroll
    for (int rb = 0; rb < 4; rb++) {
        int dl = rb * 16 + (tid >> 4);
        int tl = (tid & 15) * 4;
        float4 v = make_float4(tile[dl][tl + 0], tile[dl][tl + 1], tile[dl][tl + 2], tile[dl][tl + 3]);
        *(float4*)(out + (size_t)n * 1024 * 1024 + (size_t)(dd + dl) * 1024 + tt + tl) = v;
    }
}

extern "C" void kernel_launch(void* const* d_in, const int* in_sizes, int n_in,
                              void* d_out, int out_size, void* d_ws, size_t ws_size,
                              hipStream_t stream)
{
    const float* x       = (const float*)d_in[0];
    const float* merge_w = (const float*)d_in[1];
    const float* qkv_w   = (const float*)d_in[2];
    const float* qkv_b   = (const float*)d_in[3];
    const float* proj_w  = (const float*)d_in[4];
    const float* proj_b  = (const float*)d_in[5];
    const float* fc1_w   = (const float*)d_in[6];
    const float* fc1_b   = (const float*)d_in[7];
    const float* fc2_w   = (const float*)d_in[8];
    const float* fc2_b   = (const float*)d_in[9];
    float* out = (float*)d_out;

    // Workspace (~92 MB):
    char* ws = (char*)d_ws;
    float*  tok   = (float*)ws;                          // 16 MB  [0,16)
    bf16_t* Ab    = (bf16_t*)(ws + (16u << 20));         //  8 MB  [16,24)
    bf16_t* ob    = (bf16_t*)(ws + (24u << 20));         //  8 MB  [24,32)
    bf16_t* qkvb  = (bf16_t*)(ws + (32u << 20));         // 24 MB  [32,56) (dead after attn)
    bf16_t* vtb   = (bf16_t*)(ws + (56u << 20));         //  8 MB  [56,64) (dead after attn)
    bf16_t* hid   = (bf16_t*)(ws + (32u << 20));         // 32 MB  [32,64) (live fc1->fc2)
    bf16_t* wqkv  = (bf16_t*)(ws + (64u << 20));         // 6.29 MB
    bf16_t* wproj = wqkv + (size_t)3072 * 1024;          // 2.10 MB
    bf16_t* wfc1  = wproj + (size_t)1024 * 1024;         // 8.39 MB
    bf16_t* wfc2  = wfc1 + (size_t)4096 * 1024;          // 8.39 MB  (ends ~89.2 MB)
    bf16_t* wmrg  = (bf16_t*)(ws + (90u << 20));         // 128 KB
    float*  scl   = (float*)(ws + (91u << 20));          // 16 KB

    cvt_k<<<64, 256, 0, stream>>>(merge_w, wmrg);        // 65536 els
    patches_k<<<1024, 256, 0, stream>>>(x, Ab);
    gemm128<0><<<dim3(32, 8), 256, 0, stream>>>(Ab, wmrg, nullptr, tok, nullptr, 1024, 64);

    for (int i = 0; i < 8; i++) {
        convw_k<<<12288, 256, 0, stream>>>(
            qkv_w + (size_t)i * 3072 * 1024, proj_w + (size_t)i * 1024 * 1024,
            fc1_w + (size_t)i * 4096 * 1024, fc2_w + (size_t)i * 1024 * 4096,
            wqkv, wproj, wfc1, wfc2);

        rmsnorm_k<<<4096, 256, 0, stream>>>(tok, Ab);
        gemm128<4><<<dim3(32, 24), 256, 0, stream>>>(Ab, wqkv, qkv_b + (size_t)i * 3072,
                                                     nullptr, qkvb, 3072, 1024);
        rope_k<<<8192, 256, 0, stream>>>(qkvb);
        vtrans_k<<<1024, 256, 0, stream>>>(qkvb, vtb);
        attn_mfma<<<512, 256, 0, stream>>>(qkvb, vtb, ob);
        gemm128<2><<<dim3(32, 8), 256, 0, stream>>>(ob, wproj, proj_b + (size_t)i * 1024,
                                                    tok, nullptr, 1024, 1024);
        rmsnorm_k<<<4096, 256, 0, stream>>>(tok, Ab);
        gemm128<3><<<dim3(32, 32), 256, 0, stream>>>(Ab, wfc1, fc1_b + (size_t)i * 4096,
                                                     nullptr, hid, 4096, 1024);
        gemm128<2><<<dim3(32, 8), 256, 0, stream>>>(hid, wfc2, fc2_b + (size_t)i * 1024,
                                                    tok, nullptr, 1024, 4096);
    }
    rmsscale_k<<<4096, 256, 0, stream>>>(tok, scl);
    transpose_out_k<<<dim3(16, 16, 4), 256, 0, stream>>>(tok, scl, out);
}

// Round 2
// 2513.936 us; speedup vs baseline: 4.7450x; 1.0308x over previous
//
#include <hip/hip_runtime.h>
#include <hip/hip_bf16.h>
#include <cmath>

typedef __bf16 bf16_t;
typedef __bf16 bf16x4 __attribute__((ext_vector_type(4)));
typedef __bf16 bf16x8 __attribute__((ext_vector_type(8)));
typedef float f32x4 __attribute__((ext_vector_type(4)));

typedef const __attribute__((address_space(1))) void gv_t;
typedef __attribute__((address_space(3))) void sv_t;

#define GLDS16(g, l) __builtin_amdgcn_global_load_lds((gv_t*)(g), (sv_t*)(l), 16, 0, 0)

// ---------------- GEMM: C = A @ B^T (+bias)(+epilogue), 3-deep pipelined ----------------
// A: [M, K] bf16 row-major ; B: [N, K] bf16 row-major (weights [out,in])
// KS = K-chunk per blockIdx.z split (multiple of 32).
// EPI: 0 = store f32, no bias ; 3 = +bias, gelu, store bf16 ; 4 = +bias, store bf16 ;
//      5 = +bias(z==0 only), atomicAdd into Cf[row*1024+col] (split-K residual) ;
//      6 = +bias, fused 2D-RoPE on q/k cols (<2048), store bf16 (qkv gemm)
template <int EPI>
__global__ __launch_bounds__(256, 2) void gemm128(
    const bf16_t* __restrict__ A, const bf16_t* __restrict__ B,
    const float* __restrict__ bias, float* __restrict__ Cf,
    bf16_t* __restrict__ Cb, int N, int K, int KS)
{
    __shared__ __align__(16) bf16_t As[3][128 * 32];
    __shared__ __align__(16) bf16_t Bs[3][128 * 32];
    const int tid = threadIdx.x;
    const int bm = blockIdx.x, bn = blockIdx.y, bz = blockIdx.z;
    const int wave = tid >> 6, lane = tid & 63;
    const int wr = (wave >> 1) << 6, wc = (wave & 1) << 6;
    const int lr = lane & 15, kq = (lane >> 4) << 3;

    f32x4 acc[4][4] = {};

    const int kbeg = bz * KS;
    const bf16_t* gA = A + (size_t)(bm * 128 + (tid >> 2)) * K + (tid & 3) * 8 + kbeg;
    const bf16_t* gB = B + (size_t)(bn * 128 + (tid >> 2)) * K + (tid & 3) * 8 + kbeg;
    const bf16_t* gA2 = gA + (size_t)64 * K;
    const bf16_t* gB2 = gB + (size_t)64 * K;
    const int dst = tid * 8;
    const int nt = KS >> 5;

#define STAGE(buf, t) do { const int _k = (t) << 5;          \
        GLDS16(gA  + _k, As[buf] + dst);                     \
        GLDS16(gA2 + _k, As[buf] + dst + 2048);              \
        GLDS16(gB  + _k, Bs[buf] + dst);                     \
        GLDS16(gB2 + _k, Bs[buf] + dst + 2048); } while (0)

    STAGE(0, 0);
    if (nt > 1) STAGE(1, 1);
    int cur = 0, pre = 2;
    for (int t = 0; t < nt; ++t) {
        // wait for tile t's 4 loads (oldest); keep tile t+1's in flight
        if (t + 1 < nt) asm volatile("s_waitcnt vmcnt(4)" ::: "memory");
        else            asm volatile("s_waitcnt vmcnt(0)" ::: "memory");
        __builtin_amdgcn_s_barrier();
        if (t + 2 < nt) STAGE(pre, t + 2);

        const bf16_t* Ac = As[cur];
        const bf16_t* Bc = Bs[cur];
        bf16x8 af[4], bfr[4];
#pragma unroll
        for (int i = 0; i < 4; i++)
            af[i] = *(const bf16x8*)(Ac + (wr + i * 16 + lr) * 32 + kq);
#pragma unroll
        for (int j = 0; j < 4; j++)
            bfr[j] = *(const bf16x8*)(Bc + (wc + j * 16 + lr) * 32 + kq);
#pragma unroll
        for (int i = 0; i < 4; i++)
#pragma unroll
            for (int j = 0; j < 4; j++)
                acc[i][j] = __builtin_amdgcn_mfma_f32_16x16x32_bf16(af[i], bfr[j], acc[i][j], 0, 0, 0);

        cur = (cur == 2) ? 0 : cur + 1;
        pre = (pre == 2) ? 0 : pre + 1;
    }
#undef STAGE

    const int row0 = bm * 128 + wr + ((lane >> 4) << 2);
    const int col0 = bn * 128 + wc + lr;

    if constexpr (EPI == 6) {
        // qkv epilogue with fused 2D RoPE. Thread's 4 cols = head-rel dims
        // lr+{0,16,32,48}: pairs (lr,lr+16) rotated by pos_h, (lr+32,lr+48) by pos_w.
        float bv[4];
#pragma unroll
        for (int j = 0; j < 4; j++) bv[j] = bias[col0 + j * 16];
        const bool doRope = (col0 < 2048);
        const float invf = exp2f(-0.83048202372184056f * (float)lr);  // 10000^(-lr/16)
#pragma unroll
        for (int i = 0; i < 4; i++) {
#pragma unroll
            for (int r = 0; r < 4; r++) {
                const int row = row0 + i * 16 + r;
                float v0 = acc[i][0][r] + bv[0], v1 = acc[i][1][r] + bv[1];
                float v2 = acc[i][2][r] + bv[2], v3 = acc[i][3][r] + bv[3];
                if (doRope) {
                    const int tt = row & 1023;
                    float s0, c0, s1, c1;
                    sincosf((float)(tt >> 5) * invf, &s0, &c0);   // pos_h = t/32
                    sincosf((float)(tt & 31) * invf, &s1, &c1);   // pos_w = t%32
                    float o0 = v0 * c0 - v1 * s0, o1 = v1 * c0 + v0 * s0;
                    float o2 = v2 * c1 - v3 * s1, o3 = v3 * c1 + v2 * s1;
                    v0 = o0; v1 = o1; v2 = o2; v3 = o3;
                }
                bf16_t* cp = Cb + (size_t)row * N + col0;
                cp[0] = (bf16_t)v0; cp[16] = (bf16_t)v1;
                cp[32] = (bf16_t)v2; cp[48] = (bf16_t)v3;
            }
        }
        return;
    }

#pragma unroll
    for (int j = 0; j < 4; j++) {
        const int col = col0 + j * 16;
        float bv = 0.f;
        if constexpr (EPI == 5) { if (bz == 0) bv = bias[col]; }
        else if constexpr (EPI != 0) bv = bias[col];
#pragma unroll
        for (int i = 0; i < 4; i++) {
#pragma unroll
            for (int r = 0; r < 4; r++) {
                const int row = row0 + i * 16 + r;
                float v = acc[i][j][r] + bv;
                if constexpr (EPI == 0) {
                    Cf[(size_t)row * N + col] = v;
                } else if constexpr (EPI == 5) {
                    atomicAdd(&Cf[(size_t)row * 1024 + col], v);
                } else if constexpr (EPI == 3) {
                    float g = 0.5f * v * (1.f + tanhf(0.7978845608f * (v + 0.044715f * v * v * v)));
                    Cb[(size_t)row * N + col] = (bf16_t)g;
                } else {
                    Cb[(size_t)row * N + col] = (bf16_t)v;
                }
            }
        }
    }
}

// ---------------- per-layer weight convert f32 -> bf16 (4 tensors fused) ----------------
__global__ __launch_bounds__(256) void convw_k(
    const float* __restrict__ q, const float* __restrict__ p,
    const float* __restrict__ f1, const float* __restrict__ f2,
    bf16_t* __restrict__ oq, bf16_t* __restrict__ op,
    bf16_t* __restrict__ of1, bf16_t* __restrict__ of2)
{
    int idx = blockIdx.x * 256 + threadIdx.x;   // in float4 units; 3145728 total
    const float* src; bf16_t* dst; int off;
    if (idx < 786432)       { src = q;  dst = oq;  off = idx; }
    else if (idx < 1048576) { src = p;  dst = op;  off = idx - 786432; }
    else if (idx < 2097152) { src = f1; dst = of1; off = idx - 1048576; }
    else                    { src = f2; dst = of2; off = idx - 2097152; }
    float4 v = ((const float4*)src)[off];
    bf16x4 o; o[0] = (bf16_t)v.x; o[1] = (bf16_t)v.y; o[2] = (bf16_t)v.z; o[3] = (bf16_t)v.w;
    *(bf16x4*)(dst + (size_t)off * 4) = o;
}

// ---------------- generic f32 -> bf16 convert ----------------
__global__ __launch_bounds__(256) void cvt_k(const float* __restrict__ in, bf16_t* __restrict__ out)
{
    int idx = blockIdx.x * 256 + threadIdx.x;   // float4 units
    float4 v = ((const float4*)in)[idx];
    bf16x4 o; o[0] = (bf16_t)v.x; o[1] = (bf16_t)v.y; o[2] = (bf16_t)v.z; o[3] = (bf16_t)v.w;
    *(bf16x4*)(out + (size_t)idx * 4) = o;
}

// ---------------- SpatialMerger patch gather ----------------
__global__ __launch_bounds__(256) void patches_k(const float* __restrict__ x, bf16_t* __restrict__ out)
{
    int idx = blockIdx.x * 256 + threadIdx.x;  // 262144 total
    int cc = idx & 63, l = (idx >> 6) & 1023, n = idx >> 16;
    int c = cc >> 2, kh = (cc >> 1) & 1, kw = cc & 1;
    int hf = l >> 5, wf = l & 31;
    out[idx] = (bf16_t)x[(((n * 16 + c) * 64) + hf * 2 + kh) * 64 + wf * 2 + kw];
}

// ---------------- RMSNorm: tok f32 [4096,1024] -> bf16 ----------------
__global__ __launch_bounds__(256) void rmsnorm_k(const float* __restrict__ tok, bf16_t* __restrict__ out)
{
    int row = blockIdx.x, tid = threadIdx.x;
    float4 xv = ((const float4*)(tok + (size_t)row * 1024))[tid];
    float s = xv.x * xv.x + xv.y * xv.y + xv.z * xv.z + xv.w * xv.w;
#pragma unroll
    for (int off = 32; off > 0; off >>= 1) s += __shfl_down(s, off, 64);
    __shared__ float ws4[4];
    if ((tid & 63) == 0) ws4[tid >> 6] = s;
    __syncthreads();
    float sc = rsqrtf((ws4[0] + ws4[1] + ws4[2] + ws4[3]) * (1.f / 1024.f) + 1e-6f);
    bf16_t* o = out + (size_t)row * 1024 + tid * 4;
    bf16x4 ov;
    ov[0] = (bf16_t)(xv.x * sc); ov[1] = (bf16_t)(xv.y * sc);
    ov[2] = (bf16_t)(xv.z * sc); ov[3] = (bf16_t)(xv.w * sc);
    *(bf16x4*)o = ov;
}

// ---------------- V transpose: qkv v-section [n,t][h*64+d] -> vt [n,h,d][t] ----------------
__global__ __launch_bounds__(256) void vtrans_k(const bf16_t* __restrict__ qkv, bf16_t* __restrict__ vt)
{
    __shared__ bf16_t tile[64][72];   // 72*2=144 B rows, 16-B aligned
    const int tid = threadIdx.x, b = blockIdx.x;     // 1024 = n(4)*h(16)*tt(16)
    const int tt = b & 15, h = (b >> 4) & 15, n = b >> 8;
#pragma unroll
    for (int rr = 0; rr < 2; rr++) {
        int idx = rr * 256 + tid;
        int tr = idx >> 3, dc = (idx & 7) * 8;
        bf16x8 v = *(const bf16x8*)(qkv + (size_t)(n * 1024 + tt * 64 + tr) * 3072 + 2048 + h * 64 + dc);
        *(bf16x8*)&tile[tr][dc] = v;
    }
    __syncthreads();
#pragma unroll
    for (int rr = 0; rr < 2; rr++) {
        int idx = rr * 256 + tid;
        int d = idx >> 3, tc = (idx & 7) * 8;
        bf16x8 ov;
#pragma unroll
        for (int e = 0; e < 8; e++) ov[e] = tile[tc + e][d];
        *(bf16x8*)(vt + (size_t)((n * 16 + h) * 64 + d) * 1024 + tt * 64 + tc) = ov;
    }
}

// ---------------- MFMA flash attention ----------------
__global__ __launch_bounds__(256, 2) void attn_mfma(
    const bf16_t* __restrict__ qkv, const bf16_t* __restrict__ vt, bf16_t* __restrict__ obuf)
{
    __shared__ __align__(16) bf16_t Ks[64 * 64];     // [s][d], swizzled
    __shared__ __align__(16) bf16_t Vs[64 * 64];     // [d][s], swizzled
    __shared__ __align__(16) bf16_t Ps[4][32 * 64];  // per-wave [t][s], swizzled

    const int tid = threadIdx.x, wave = tid >> 6, lane = tid & 63;
    const int lr = lane & 15, g = lane >> 4;
    const int blk = blockIdx.x;
    const int qb = blk & 7, h = (blk >> 3) & 15, n = blk >> 7;
    const int t0 = qb * 128 + wave * 32;             // wave's first q row (within head)

    // ---- Q fragments (B-operand layout), pre-scaled by 1/sqrt(64)=0.125
    bf16x8 bq[2][2];
#pragma unroll
    for (int j = 0; j < 2; j++)
#pragma unroll
        for (int kk = 0; kk < 2; kk++) {
            bf16x8 v = *(const bf16x8*)(qkv + (size_t)(n * 1024 + t0 + j * 16 + lr) * 3072 + h * 64 + kk * 32 + g * 8);
#pragma unroll
            for (int e = 0; e < 8; e++) v[e] = (bf16_t)((float)v[e] * 0.125f);
            bq[j][kk] = v;
        }

    f32x4 o[2][4] = {};
    float m[2] = {-1e30f, -1e30f}, l[2] = {0.f, 0.f};

    const int sr = tid >> 3, pcb = tid & 7;
    const int scb = (pcb ^ (sr & 7)) * 8;            // swizzled source column (elements)
    const bf16_t* ksrc = qkv + (size_t)(n * 1024 + sr) * 3072 + 1024 + h * 64 + scb;
    const bf16_t* vsrc = vt + (size_t)((n * 16 + h) * 64 + sr) * 1024 + scb;
    bf16_t* kdst = Ks + tid * 8;
    bf16_t* vdst = Vs + tid * 8;

    for (int s0 = 0; s0 < 1024; s0 += 64) {
        __syncthreads();
        GLDS16(ksrc + (size_t)s0 * 3072, kdst);
        GLDS16(ksrc + (size_t)(s0 + 32) * 3072, kdst + 2048);
        GLDS16(vsrc + s0, vdst);
        GLDS16(vsrc + s0 + (size_t)32 * 1024, vdst + 2048);
        __syncthreads();

        // ---- S^T = K @ Q^T  (row=s: 4 blocks, col=t: 2 blocks)
        f32x4 st[4][2] = {};
#pragma unroll
        for (int kk = 0; kk < 2; kk++) {
            bf16x8 ak[4];
#pragma unroll
            for (int i = 0; i < 4; i++)
                ak[i] = *(const bf16x8*)((const char*)Ks + (i * 16 + lr) * 128 + (((kk * 4 + g) ^ (lr & 7)) * 16));
#pragma unroll
            for (int i = 0; i < 4; i++)
#pragma unroll
                for (int j = 0; j < 2; j++)
                    st[i][j] = __builtin_amdgcn_mfma_f32_16x16x32_bf16(ak[i], bq[j][kk], st[i][j], 0, 0, 0);
        }

        // ---- online softmax per t-column; write P (bf16) to per-wave LDS as [t][s]
        float al2[2];
#pragma unroll
        for (int j = 0; j < 2; j++) {
            float rm = st[0][j][0];
#pragma unroll
            for (int i = 0; i < 4; i++)
#pragma unroll
                for (int r = 0; r < 4; r++) rm = fmaxf(rm, st[i][j][r]);
            rm = fmaxf(rm, __shfl_xor(rm, 16, 64));
            rm = fmaxf(rm, __shfl_xor(rm, 32, 64));
            float mn = fmaxf(m[j], rm);
            float al = __expf(m[j] - mn);
            m[j] = mn; al2[j] = al;
            float ps = 0.f;
#pragma unroll
            for (int i = 0; i < 4; i++) {
                bf16x4 pk;
#pragma unroll
                for (int r = 0; r < 4; r++) {
                    float p = __expf(st[i][j][r] - mn);
                    bf16_t pb = (bf16_t)p;
                    pk[r] = pb;
                    ps += (float)pb;
                }
                *(bf16x4*)((char*)&Ps[wave][0] + (j * 16 + lr) * 128 +
                           (((i * 2 + (g >> 1)) ^ (lr & 7)) * 16) + (g & 1) * 8) = pk;
            }
            ps += __shfl_xor(ps, 16, 64);
            ps += __shfl_xor(ps, 32, 64);
            l[j] = l[j] * al + ps;
        }

        // ---- rescale O by alpha
#pragma unroll
        for (int ti = 0; ti < 2; ti++)
#pragma unroll
            for (int r = 0; r < 4; r++) {
                float av = __shfl(al2[ti], g * 4 + r, 64);
#pragma unroll
                for (int dj = 0; dj < 4; dj++) o[ti][dj][r] *= av;
            }

        // ---- O += P @ V
#pragma unroll
        for (int kk = 0; kk < 2; kk++) {
            bf16x8 ap[2], bv[4];
#pragma unroll
            for (int ti = 0; ti < 2; ti++)
                ap[ti] = *(const bf16x8*)((const char*)&Ps[wave][0] + (ti * 16 + lr) * 128 +
                                          (((kk * 4 + g) ^ (lr & 7)) * 16));
#pragma unroll
            for (int dj = 0; dj < 4; dj++)
                bv[dj] = *(const bf16x8*)((const char*)Vs + (dj * 16 + lr) * 128 +
                                          (((kk * 4 + g) ^ (lr & 7)) * 16));
#pragma unroll
            for (int ti = 0; ti < 2; ti++)
#pragma unroll
                for (int dj = 0; dj < 4; dj++)
                    o[ti][dj] = __builtin_amdgcn_mfma_f32_16x16x32_bf16(ap[ti], bv[dj], o[ti][dj], 0, 0, 0);
        }
    }

    // ---- epilogue: O /= l, store bf16
#pragma unroll
    for (int ti = 0; ti < 2; ti++)
#pragma unroll
        for (int r = 0; r < 4; r++) {
            float lv = __shfl(l[ti], g * 4 + r, 64);
            float inv = 1.f / lv;
            const int trow = n * 1024 + qb * 128 + wave * 32 + ti * 16 + g * 4 + r;
#pragma unroll
            for (int dj = 0; dj < 4; dj++)
                obuf[(size_t)trow * 1024 + h * 64 + dj * 16 + lr] = (bf16_t)(o[ti][dj][r] * inv);
        }
}

// ---------------- final rmsnorm scale per token ----------------
__global__ __launch_bounds__(256) void rmsscale_k(const float* __restrict__ tok, float* __restrict__ scale)
{
    int row = blockIdx.x, tid = threadIdx.x;
    float4 xv = ((const float4*)(tok + (size_t)row * 1024))[tid];
    float s = xv.x * xv.x + xv.y * xv.y + xv.z * xv.z + xv.w * xv.w;
#pragma unroll
    for (int off = 32; off > 0; off >>= 1) s += __shfl_down(s, off, 64);
    __shared__ float ws4[4];
    if ((tid & 63) == 0) ws4[tid >> 6] = s;
    __syncthreads();
    if (tid == 0)
        scale[row] = rsqrtf((ws4[0] + ws4[1] + ws4[2] + ws4[3]) * (1.f / 1024.f) + 1e-6f);
}

// ---------------- scale + transpose: out f32 [n][d][t] = tok[n][t][d]*scale[n,t] ----------------
__global__ __launch_bounds__(256) void transpose_out_k(const float* __restrict__ tok,
                                                       const float* __restrict__ scale,
                                                       float* __restrict__ out)
{
    __shared__ float tile[64][65];
    const int tid = threadIdx.x;
    const int tt = blockIdx.x * 64, dd = blockIdx.y * 64, n = blockIdx.z;
#pragma unroll
    for (int rb = 0; rb < 4; rb++) {
        int tl = rb * 16 + (tid >> 4);
        int cl = (tid & 15) * 4;
        float4 v = *(const float4*)(tok + (size_t)(n * 1024 + tt + tl) * 1024 + dd + cl);
        float sc = scale[n * 1024 + tt + tl];
        tile[cl + 0][tl] = v.x * sc;
        tile[cl + 1][tl] = v.y * sc;
        tile[cl + 2][tl] = v.z * sc;
        tile[cl + 3][tl] = v.w * sc;
    }
    __syncthreads();
#pragma unroll
    for (int rb = 0; rb < 4; rb++) {
        int dl = rb * 16 + (tid >> 4);
        int tl = (tid & 15) * 4;
        float4 v = make_float4(tile[dl][tl + 0], tile[dl][tl + 1], tile[dl][tl + 2], tile[dl][tl + 3]);
        *(float4*)(out + (size_t)n * 1024 * 1024 + (size_t)(dd + dl) * 1024 + tt + tl) = v;
    }
}

extern "C" void kernel_launch(void* const* d_in, const int* in_sizes, int n_in,
                              void* d_out, int out_size, void* d_ws, size_t ws_size,
                              hipStream_t stream)
{
    const float* x       = (const float*)d_in[0];
    const float* merge_w = (const float*)d_in[1];
    const float* qkv_w   = (const float*)d_in[2];
    const float* qkv_b   = (const float*)d_in[3];
    const float* proj_w  = (const float*)d_in[4];
    const float* proj_b  = (const float*)d_in[5];
    const float* fc1_w   = (const float*)d_in[6];
    const float* fc1_b   = (const float*)d_in[7];
    const float* fc2_w   = (const float*)d_in[8];
    const float* fc2_b   = (const float*)d_in[9];
    float* out = (float*)d_out;

    // Workspace (~92 MB):
    char* ws = (char*)d_ws;
    float*  tok   = (float*)ws;                          // 16 MB  [0,16)
    bf16_t* Ab    = (bf16_t*)(ws + (16u << 20));         //  8 MB  [16,24)
    bf16_t* ob    = (bf16_t*)(ws + (24u << 20));         //  8 MB  [24,32)
    bf16_t* qkvb  = (bf16_t*)(ws + (32u << 20));         // 24 MB  [32,56) (dead after attn)
    bf16_t* vtb   = (bf16_t*)(ws + (56u << 20));         //  8 MB  [56,64) (dead after attn)
    bf16_t* hid   = (bf16_t*)(ws + (32u << 20));         // 32 MB  [32,64) (live fc1->fc2)
    bf16_t* wqkv  = (bf16_t*)(ws + (64u << 20));         // 6.29 MB
    bf16_t* wproj = wqkv + (size_t)3072 * 1024;          // 2.10 MB
    bf16_t* wfc1  = wproj + (size_t)1024 * 1024;         // 8.39 MB
    bf16_t* wfc2  = wfc1 + (size_t)4096 * 1024;          // 8.39 MB  (ends ~89.2 MB)
    bf16_t* wmrg  = (bf16_t*)(ws + (90u << 20));         // 128 KB
    float*  scl   = (float*)(ws + (91u << 20));          // 16 KB

    cvt_k<<<64, 256, 0, stream>>>(merge_w, wmrg);        // 65536 els
    patches_k<<<1024, 256, 0, stream>>>(x, Ab);
    gemm128<0><<<dim3(32, 8, 1), 256, 0, stream>>>(Ab, wmrg, nullptr, tok, nullptr, 1024, 64, 64);

    for (int i = 0; i < 8; i++) {
        convw_k<<<12288, 256, 0, stream>>>(
            qkv_w + (size_t)i * 3072 * 1024, proj_w + (size_t)i * 1024 * 1024,
            fc1_w + (size_t)i * 4096 * 1024, fc2_w + (size_t)i * 1024 * 4096,
            wqkv, wproj, wfc1, wfc2);

        rmsnorm_k<<<4096, 256, 0, stream>>>(tok, Ab);
        gemm128<6><<<dim3(32, 24, 1), 256, 0, stream>>>(Ab, wqkv, qkv_b + (size_t)i * 3072,
                                                        nullptr, qkvb, 3072, 1024, 1024);
        vtrans_k<<<1024, 256, 0, stream>>>(qkvb, vtb);
        attn_mfma<<<512, 256, 0, stream>>>(qkvb, vtb, ob);
        gemm128<5><<<dim3(32, 8, 2), 256, 0, stream>>>(ob, wproj, proj_b + (size_t)i * 1024,
                                                       tok, nullptr, 1024, 1024, 512);
        rmsnorm_k<<<4096, 256, 0, stream>>>(tok, Ab);
        gemm128<3><<<dim3(32, 32, 1), 256, 0, stream>>>(Ab, wfc1, fc1_b + (size_t)i * 4096,
                                                        nullptr, hid, 4096, 1024, 1024);
        gemm128<5><<<dim3(32, 8, 2), 256, 0, stream>>>(hid, wfc2, fc2_b + (size_t)i * 1024,
                                                       tok, nullptr, 1024, 4096, 2048);
    }
    rmsscale_k<<<4096, 256, 0, stream>>>(tok, scl);
    transpose_out_k<<<dim3(16, 16, 4), 256, 0, stream>>>(tok, scl, out);
}

// Round 3
// 2470.320 us; speedup vs baseline: 4.8288x; 1.0177x over previous
//
#include <hip/hip_runtime.h>
#include <hip/hip_bf16.h>
#include <cmath>

typedef __bf16 bf16_t;
typedef __bf16 bf16x4 __attribute__((ext_vector_type(4)));
typedef __bf16 bf16x8 __attribute__((ext_vector_type(8)));
typedef float f32x4 __attribute__((ext_vector_type(4)));

typedef const __attribute__((address_space(1))) void gv_t;
typedef __attribute__((address_space(3))) void sv_t;

#define GLDS16(g, l) __builtin_amdgcn_global_load_lds((gv_t*)(g), (sv_t*)(l), 16, 0, 0)

// ---------------- GEMM: C = A @ B^T (+bias)(+epilogue), 3-deep pipelined ----------------
// A: [M, K] bf16 row-major ; B: [N, K] bf16 row-major (weights [out,in])
// KS = K-chunk per blockIdx.z split (multiple of 32).
// EPI: 0 = store f32, no bias ;
//      3 = +bias, gelu, store bf16 ;
//      5 = split-K, race-free: z==0 -> Cf[row*1024+col] += v + bias ; z==1 -> Cf2[row*1024+col] = v ;
//      6 = +bias, fused 2D-RoPE on q/k cols (<2048), store bf16 (qkv gemm)
template <int EPI>
__global__ __launch_bounds__(256, 2) void gemm128(
    const bf16_t* __restrict__ A, const bf16_t* __restrict__ B,
    const float* __restrict__ bias, float* __restrict__ Cf,
    float* __restrict__ Cf2, bf16_t* __restrict__ Cb, int N, int K, int KS)
{
    __shared__ __align__(16) bf16_t As[3][128 * 32];
    __shared__ __align__(16) bf16_t Bs[3][128 * 32];
    const int tid = threadIdx.x;
    const int bm = blockIdx.x, bn = blockIdx.y, bz = blockIdx.z;
    const int wave = tid >> 6, lane = tid & 63;
    const int wr = (wave >> 1) << 6, wc = (wave & 1) << 6;
    const int lr = lane & 15, kq = (lane >> 4) << 3;

    f32x4 acc[4][4] = {};

    const int kbeg = bz * KS;
    const bf16_t* gA = A + (size_t)(bm * 128 + (tid >> 2)) * K + (tid & 3) * 8 + kbeg;
    const bf16_t* gB = B + (size_t)(bn * 128 + (tid >> 2)) * K + (tid & 3) * 8 + kbeg;
    const bf16_t* gA2 = gA + (size_t)64 * K;
    const bf16_t* gB2 = gB + (size_t)64 * K;
    const int dst = tid * 8;
    const int nt = KS >> 5;

#define STAGE(buf, t) do { const int _k = (t) << 5;          \
        GLDS16(gA  + _k, As[buf] + dst);                     \
        GLDS16(gA2 + _k, As[buf] + dst + 2048);              \
        GLDS16(gB  + _k, Bs[buf] + dst);                     \
        GLDS16(gB2 + _k, Bs[buf] + dst + 2048); } while (0)

    STAGE(0, 0);
    if (nt > 1) STAGE(1, 1);
    int cur = 0, pre = 2;
    for (int t = 0; t < nt; ++t) {
        // wait for tile t's 4 loads (oldest); keep tile t+1's in flight
        if (t + 1 < nt) asm volatile("s_waitcnt vmcnt(4)" ::: "memory");
        else            asm volatile("s_waitcnt vmcnt(0)" ::: "memory");
        __builtin_amdgcn_s_barrier();
        if (t + 2 < nt) STAGE(pre, t + 2);

        const bf16_t* Ac = As[cur];
        const bf16_t* Bc = Bs[cur];
        bf16x8 af[4], bfr[4];
#pragma unroll
        for (int i = 0; i < 4; i++)
            af[i] = *(const bf16x8*)(Ac + (wr + i * 16 + lr) * 32 + kq);
#pragma unroll
        for (int j = 0; j < 4; j++)
            bfr[j] = *(const bf16x8*)(Bc + (wc + j * 16 + lr) * 32 + kq);
#pragma unroll
        for (int i = 0; i < 4; i++)
#pragma unroll
            for (int j = 0; j < 4; j++)
                acc[i][j] = __builtin_amdgcn_mfma_f32_16x16x32_bf16(af[i], bfr[j], acc[i][j], 0, 0, 0);

        cur = (cur == 2) ? 0 : cur + 1;
        pre = (pre == 2) ? 0 : pre + 1;
    }
#undef STAGE

    const int row0 = bm * 128 + wr + ((lane >> 4) << 2);
    const int col0 = bn * 128 + wc + lr;

    if constexpr (EPI == 6) {
        // qkv epilogue with fused 2D RoPE. Thread's 4 cols = head-rel dims
        // lr+{0,16,32,48}: pairs (lr,lr+16) rotated by pos_h, (lr+32,lr+48) by pos_w.
        float bv[4];
#pragma unroll
        for (int j = 0; j < 4; j++) bv[j] = bias[col0 + j * 16];
        const bool doRope = (col0 < 2048);
        const float invf = exp2f(-0.83048202372184056f * (float)lr);  // 10000^(-lr/16)
#pragma unroll
        for (int i = 0; i < 4; i++) {
#pragma unroll
            for (int r = 0; r < 4; r++) {
                const int row = row0 + i * 16 + r;
                float v0 = acc[i][0][r] + bv[0], v1 = acc[i][1][r] + bv[1];
                float v2 = acc[i][2][r] + bv[2], v3 = acc[i][3][r] + bv[3];
                if (doRope) {
                    const int tt = row & 1023;
                    float s0, c0, s1, c1;
                    sincosf((float)(tt >> 5) * invf, &s0, &c0);   // pos_h = t/32
                    sincosf((float)(tt & 31) * invf, &s1, &c1);   // pos_w = t%32
                    float o0 = v0 * c0 - v1 * s0, o1 = v1 * c0 + v0 * s0;
                    float o2 = v2 * c1 - v3 * s1, o3 = v3 * c1 + v2 * s1;
                    v0 = o0; v1 = o1; v2 = o2; v3 = o3;
                }
                bf16_t* cp = Cb + (size_t)row * N + col0;
                cp[0] = (bf16_t)v0; cp[16] = (bf16_t)v1;
                cp[32] = (bf16_t)v2; cp[48] = (bf16_t)v3;
            }
        }
        return;
    }

#pragma unroll
    for (int j = 0; j < 4; j++) {
        const int col = col0 + j * 16;
        float bv = 0.f;
        if constexpr (EPI == 3) bv = bias[col];
        if constexpr (EPI == 5) { if (bz == 0) bv = bias[col]; }
#pragma unroll
        for (int i = 0; i < 4; i++) {
#pragma unroll
            for (int r = 0; r < 4; r++) {
                const int row = row0 + i * 16 + r;
                float v = acc[i][j][r] + bv;
                if constexpr (EPI == 0) {
                    Cf[(size_t)row * N + col] = v;
                } else if constexpr (EPI == 5) {
                    if (bz == 0) {
                        float* dp = Cf + (size_t)row * 1024 + col;
                        *dp += v;                      // unique owner: race-free RMW
                    } else {
                        Cf2[(size_t)row * 1024 + col] = v;
                    }
                } else if constexpr (EPI == 3) {
                    float g = 0.5f * v * (1.f + tanhf(0.7978845608f * (v + 0.044715f * v * v * v)));
                    Cb[(size_t)row * N + col] = (bf16_t)g;
                }
            }
        }
    }
}

// ---------------- per-layer weight convert f32 -> bf16 (4 tensors fused) ----------------
__global__ __launch_bounds__(256) void convw_k(
    const float* __restrict__ q, const float* __restrict__ p,
    const float* __restrict__ f1, const float* __restrict__ f2,
    bf16_t* __restrict__ oq, bf16_t* __restrict__ op,
    bf16_t* __restrict__ of1, bf16_t* __restrict__ of2)
{
    int idx = blockIdx.x * 256 + threadIdx.x;   // in float4 units; 3145728 total
    const float* src; bf16_t* dst; int off;
    if (idx < 786432)       { src = q;  dst = oq;  off = idx; }
    else if (idx < 1048576) { src = p;  dst = op;  off = idx - 786432; }
    else if (idx < 2097152) { src = f1; dst = of1; off = idx - 1048576; }
    else                    { src = f2; dst = of2; off = idx - 2097152; }
    float4 v = ((const float4*)src)[off];
    bf16x4 o; o[0] = (bf16_t)v.x; o[1] = (bf16_t)v.y; o[2] = (bf16_t)v.z; o[3] = (bf16_t)v.w;
    *(bf16x4*)(dst + (size_t)off * 4) = o;
}

// ---------------- generic f32 -> bf16 convert ----------------
__global__ __launch_bounds__(256) void cvt_k(const float* __restrict__ in, bf16_t* __restrict__ out)
{
    int idx = blockIdx.x * 256 + threadIdx.x;   // float4 units
    float4 v = ((const float4*)in)[idx];
    bf16x4 o; o[0] = (bf16_t)v.x; o[1] = (bf16_t)v.y; o[2] = (bf16_t)v.z; o[3] = (bf16_t)v.w;
    *(bf16x4*)(out + (size_t)idx * 4) = o;
}

// ---------------- SpatialMerger patch gather ----------------
__global__ __launch_bounds__(256) void patches_k(const float* __restrict__ x, bf16_t* __restrict__ out)
{
    int idx = blockIdx.x * 256 + threadIdx.x;  // 262144 total
    int cc = idx & 63, l = (idx >> 6) & 1023, n = idx >> 16;
    int c = cc >> 2, kh = (cc >> 1) & 1, kw = cc & 1;
    int hf = l >> 5, wf = l & 31;
    out[idx] = (bf16_t)x[(((n * 16 + c) * 64) + hf * 2 + kh) * 64 + wf * 2 + kw];
}

// ---------------- RMSNorm (+optional partial-sum fold): tok(+p) -> tok, bf16 out ----------------
__global__ __launch_bounds__(256) void rmsnorm_k(float* __restrict__ tok,
                                                 const float* __restrict__ p,
                                                 bf16_t* __restrict__ out)
{
    int row = blockIdx.x, tid = threadIdx.x;
    float4 xv = ((const float4*)(tok + (size_t)row * 1024))[tid];
    if (p) {
        float4 pv = ((const float4*)(p + (size_t)row * 1024))[tid];
        xv.x += pv.x; xv.y += pv.y; xv.z += pv.z; xv.w += pv.w;
        ((float4*)(tok + (size_t)row * 1024))[tid] = xv;
    }
    float s = xv.x * xv.x + xv.y * xv.y + xv.z * xv.z + xv.w * xv.w;
#pragma unroll
    for (int off = 32; off > 0; off >>= 1) s += __shfl_down(s, off, 64);
    __shared__ float ws4[4];
    if ((tid & 63) == 0) ws4[tid >> 6] = s;
    __syncthreads();
    float sc = rsqrtf((ws4[0] + ws4[1] + ws4[2] + ws4[3]) * (1.f / 1024.f) + 1e-6f);
    bf16_t* o = out + (size_t)row * 1024 + tid * 4;
    bf16x4 ov;
    ov[0] = (bf16_t)(xv.x * sc); ov[1] = (bf16_t)(xv.y * sc);
    ov[2] = (bf16_t)(xv.z * sc); ov[3] = (bf16_t)(xv.w * sc);
    *(bf16x4*)o = ov;
}

// ---------------- V transpose: qkv v-section [n,t][h*64+d] -> vt [n,h,d][t] ----------------
__global__ __launch_bounds__(256) void vtrans_k(const bf16_t* __restrict__ qkv, bf16_t* __restrict__ vt)
{
    __shared__ bf16_t tile[64][72];   // 72*2=144 B rows, 16-B aligned
    const int tid = threadIdx.x, b = blockIdx.x;     // 1024 = n(4)*h(16)*tt(16)
    const int tt = b & 15, h = (b >> 4) & 15, n = b >> 8;
#pragma unroll
    for (int rr = 0; rr < 2; rr++) {
        int idx = rr * 256 + tid;
        int tr = idx >> 3, dc = (idx & 7) * 8;
        bf16x8 v = *(const bf16x8*)(qkv + (size_t)(n * 1024 + tt * 64 + tr) * 3072 + 2048 + h * 64 + dc);
        *(bf16x8*)&tile[tr][dc] = v;
    }
    __syncthreads();
#pragma unroll
    for (int rr = 0; rr < 2; rr++) {
        int idx = rr * 256 + tid;
        int d = idx >> 3, tc = (idx & 7) * 8;
        bf16x8 ov;
#pragma unroll
        for (int e = 0; e < 8; e++) ov[e] = tile[tc + e][d];
        *(bf16x8*)(vt + (size_t)((n * 16 + h) * 64 + d) * 1024 + tt * 64 + tc) = ov;
    }
}

// ---------------- MFMA flash attention ----------------
__global__ __launch_bounds__(256, 2) void attn_mfma(
    const bf16_t* __restrict__ qkv, const bf16_t* __restrict__ vt, bf16_t* __restrict__ obuf)
{
    __shared__ __align__(16) bf16_t Ks[64 * 64];     // [s][d], swizzled
    __shared__ __align__(16) bf16_t Vs[64 * 64];     // [d][s], swizzled
    __shared__ __align__(16) bf16_t Ps[4][32 * 64];  // per-wave [t][s], swizzled

    const int tid = threadIdx.x, wave = tid >> 6, lane = tid & 63;
    const int lr = lane & 15, g = lane >> 4;
    const int blk = blockIdx.x;
    const int qb = blk & 7, h = (blk >> 3) & 15, n = blk >> 7;
    const int t0 = qb * 128 + wave * 32;             // wave's first q row (within head)

    // ---- Q fragments (B-operand layout), pre-scaled by 1/sqrt(64)=0.125
    bf16x8 bq[2][2];
#pragma unroll
    for (int j = 0; j < 2; j++)
#pragma unroll
        for (int kk = 0; kk < 2; kk++) {
            bf16x8 v = *(const bf16x8*)(qkv + (size_t)(n * 1024 + t0 + j * 16 + lr) * 3072 + h * 64 + kk * 32 + g * 8);
#pragma unroll
            for (int e = 0; e < 8; e++) v[e] = (bf16_t)((float)v[e] * 0.125f);
            bq[j][kk] = v;
        }

    f32x4 o[2][4] = {};
    float m[2] = {-1e30f, -1e30f}, l[2] = {0.f, 0.f};

    const int sr = tid >> 3, pcb = tid & 7;
    const int scb = (pcb ^ (sr & 7)) * 8;            // swizzled source column (elements)
    const bf16_t* ksrc = qkv + (size_t)(n * 1024 + sr) * 3072 + 1024 + h * 64 + scb;
    const bf16_t* vsrc = vt + (size_t)((n * 16 + h) * 64 + sr) * 1024 + scb;
    bf16_t* kdst = Ks + tid * 8;
    bf16_t* vdst = Vs + tid * 8;

    for (int s0 = 0; s0 < 1024; s0 += 64) {
        __syncthreads();
        GLDS16(ksrc + (size_t)s0 * 3072, kdst);
        GLDS16(ksrc + (size_t)(s0 + 32) * 3072, kdst + 2048);
        GLDS16(vsrc + s0, vdst);
        GLDS16(vsrc + s0 + (size_t)32 * 1024, vdst + 2048);
        __syncthreads();

        // ---- S^T = K @ Q^T  (row=s: 4 blocks, col=t: 2 blocks)
        f32x4 st[4][2] = {};
#pragma unroll
        for (int kk = 0; kk < 2; kk++) {
            bf16x8 ak[4];
#pragma unroll
            for (int i = 0; i < 4; i++)
                ak[i] = *(const bf16x8*)((const char*)Ks + (i * 16 + lr) * 128 + (((kk * 4 + g) ^ (lr & 7)) * 16));
#pragma unroll
            for (int i = 0; i < 4; i++)
#pragma unroll
                for (int j = 0; j < 2; j++)
                    st[i][j] = __builtin_amdgcn_mfma_f32_16x16x32_bf16(ak[i], bq[j][kk], st[i][j], 0, 0, 0);
        }

        // ---- online softmax per t-column; write P (bf16) to per-wave LDS as [t][s]
        float al2[2];
#pragma unroll
        for (int j = 0; j < 2; j++) {
            float rm = st[0][j][0];
#pragma unroll
            for (int i = 0; i < 4; i++)
#pragma unroll
                for (int r = 0; r < 4; r++) rm = fmaxf(rm, st[i][j][r]);
            rm = fmaxf(rm, __shfl_xor(rm, 16, 64));
            rm = fmaxf(rm, __shfl_xor(rm, 32, 64));
            float mn = fmaxf(m[j], rm);
            float al = __expf(m[j] - mn);
            m[j] = mn; al2[j] = al;
            float ps = 0.f;
#pragma unroll
            for (int i = 0; i < 4; i++) {
                bf16x4 pk;
#pragma unroll
                for (int r = 0; r < 4; r++) {
                    float p = __expf(st[i][j][r] - mn);
                    bf16_t pb = (bf16_t)p;
                    pk[r] = pb;
                    ps += (float)pb;
                }
                *(bf16x4*)((char*)&Ps[wave][0] + (j * 16 + lr) * 128 +
                           (((i * 2 + (g >> 1)) ^ (lr & 7)) * 16) + (g & 1) * 8) = pk;
            }
            ps += __shfl_xor(ps, 16, 64);
            ps += __shfl_xor(ps, 32, 64);
            l[j] = l[j] * al + ps;
        }

        // ---- rescale O by alpha
#pragma unroll
        for (int ti = 0; ti < 2; ti++)
#pragma unroll
            for (int r = 0; r < 4; r++) {
                float av = __shfl(al2[ti], g * 4 + r, 64);
#pragma unroll
                for (int dj = 0; dj < 4; dj++) o[ti][dj][r] *= av;
            }

        // ---- O += P @ V
#pragma unroll
        for (int kk = 0; kk < 2; kk++) {
            bf16x8 ap[2], bv[4];
#pragma unroll
            for (int ti = 0; ti < 2; ti++)
                ap[ti] = *(const bf16x8*)((const char*)&Ps[wave][0] + (ti * 16 + lr) * 128 +
                                          (((kk * 4 + g) ^ (lr & 7)) * 16));
#pragma unroll
            for (int dj = 0; dj < 4; dj++)
                bv[dj] = *(const bf16x8*)((const char*)Vs + (dj * 16 + lr) * 128 +
                                          (((kk * 4 + g) ^ (lr & 7)) * 16));
#pragma unroll
            for (int ti = 0; ti < 2; ti++)
#pragma unroll
                for (int dj = 0; dj < 4; dj++)
                    o[ti][dj] = __builtin_amdgcn_mfma_f32_16x16x32_bf16(ap[ti], bv[dj], o[ti][dj], 0, 0, 0);
        }
    }

    // ---- epilogue: O /= l, store bf16
#pragma unroll
    for (int ti = 0; ti < 2; ti++)
#pragma unroll
        for (int r = 0; r < 4; r++) {
            float lv = __shfl(l[ti], g * 4 + r, 64);
            float inv = 1.f / lv;
            const int trow = n * 1024 + qb * 128 + wave * 32 + ti * 16 + g * 4 + r;
#pragma unroll
            for (int dj = 0; dj < 4; dj++)
                obuf[(size_t)trow * 1024 + h * 64 + dj * 16 + lr] = (bf16_t)(o[ti][dj][r] * inv);
        }
}

// ---------------- final rmsnorm scale per token (+fold fc2 partial) ----------------
__global__ __launch_bounds__(256) void rmsscale_k(float* __restrict__ tok,
                                                  const float* __restrict__ p,
                                                  float* __restrict__ scale)
{
    int row = blockIdx.x, tid = threadIdx.x;
    float4 xv = ((const float4*)(tok + (size_t)row * 1024))[tid];
    if (p) {
        float4 pv = ((const float4*)(p + (size_t)row * 1024))[tid];
        xv.x += pv.x; xv.y += pv.y; xv.z += pv.z; xv.w += pv.w;
        ((float4*)(tok + (size_t)row * 1024))[tid] = xv;
    }
    float s = xv.x * xv.x + xv.y * xv.y + xv.z * xv.z + xv.w * xv.w;
#pragma unroll
    for (int off = 32; off > 0; off >>= 1) s += __shfl_down(s, off, 64);
    __shared__ float ws4[4];
    if ((tid & 63) == 0) ws4[tid >> 6] = s;
    __syncthreads();
    if (tid == 0)
        scale[row] = rsqrtf((ws4[0] + ws4[1] + ws4[2] + ws4[3]) * (1.f / 1024.f) + 1e-6f);
}

// ---------------- scale + transpose: out f32 [n][d][t] = tok[n][t][d]*scale[n,t] ----------------
__global__ __launch_bounds__(256) void transpose_out_k(const float* __restrict__ tok,
                                                       const float* __restrict__ scale,
                                                       float* __restrict__ out)
{
    __shared__ float tile[64][65];
    const int tid = threadIdx.x;
    const int tt = blockIdx.x * 64, dd = blockIdx.y * 64, n = blockIdx.z;
#pragma unroll
    for (int rb = 0; rb < 4; rb++) {
        int tl = rb * 16 + (tid >> 4);
        int cl = (tid & 15) * 4;
        float4 v = *(const float4*)(tok + (size_t)(n * 1024 + tt + tl) * 1024 + dd + cl);
        float sc = scale[n * 1024 + tt + tl];
        tile[cl + 0][tl] = v.x * sc;
        tile[cl + 1][tl] = v.y * sc;
        tile[cl + 2][tl] = v.z * sc;
        tile[cl + 3][tl] = v.w * sc;
    }
    __syncthreads();
#pragma unroll
    for (int rb = 0; rb < 4; rb++) {
        int dl = rb * 16 + (tid >> 4);
        int tl = (tid & 15) * 4;
        float4 v = make_float4(tile[dl][tl + 0], tile[dl][tl + 1], tile[dl][tl + 2], tile[dl][tl + 3]);
        *(float4*)(out + (size_t)n * 1024 * 1024 + (size_t)(dd + dl) * 1024 + tt + tl) = v;
    }
}

extern "C" void kernel_launch(void* const* d_in, const int* in_sizes, int n_in,
                              void* d_out, int out_size, void* d_ws, size_t ws_size,
                              hipStream_t stream)
{
    const float* x       = (const float*)d_in[0];
    const float* merge_w = (const float*)d_in[1];
    const float* qkv_w   = (const float*)d_in[2];
    const float* qkv_b   = (const float*)d_in[3];
    const float* proj_w  = (const float*)d_in[4];
    const float* proj_b  = (const float*)d_in[5];
    const float* fc1_w   = (const float*)d_in[6];
    const float* fc1_b   = (const float*)d_in[7];
    const float* fc2_w   = (const float*)d_in[8];
    const float* fc2_b   = (const float*)d_in[9];
    float* out = (float*)d_out;

    // Workspace (~91 MB), aliased by liveness:
    //  [0,16)   tok f32
    //  [16,32)  pfc2 f32 (fc2 z1 partial; consumed by next-layer rmsnorm1)
    //           also vtb bf16 [16,24) (vtrans->attn) and A2 bf16 [16,24) (rmsnorm2->fc1)
    //  [24,32)  ob bf16 (attn out -> proj A)
    //  [32,40)  A1 bf16 (rmsnorm1 out -> qkv A; also patches for merge)
    //  [40,64)  qkvb bf16 (qkv out; dead after attn)
    //           also pproj f32 [40,56) (proj z1 partial -> rmsnorm2)
    //  [32,64)  hid bf16 (fc1 out -> fc2 A; overwrites A1/pproj after both dead)
    //  [64,~89.2) weights bf16 ; [90) wmrg ; [91) scl
    char* ws = (char*)d_ws;
    float*  tok   = (float*)ws;
    float*  pfc2  = (float*)(ws + (16u << 20));
    bf16_t* vtb   = (bf16_t*)(ws + (16u << 20));
    bf16_t* A2    = (bf16_t*)(ws + (16u << 20));
    bf16_t* ob    = (bf16_t*)(ws + (24u << 20));
    bf16_t* A1    = (bf16_t*)(ws + (32u << 20));
    bf16_t* qkvb  = (bf16_t*)(ws + (40u << 20));
    float*  pproj = (float*)(ws + (40u << 20));
    bf16_t* hid   = (bf16_t*)(ws + (32u << 20));
    bf16_t* wqkv  = (bf16_t*)(ws + (64u << 20));
    bf16_t* wproj = wqkv + (size_t)3072 * 1024;
    bf16_t* wfc1  = wproj + (size_t)1024 * 1024;
    bf16_t* wfc2  = wfc1 + (size_t)4096 * 1024;
    bf16_t* wmrg  = (bf16_t*)(ws + (90u << 20));
    float*  scl   = (float*)(ws + (91u << 20));

    cvt_k<<<64, 256, 0, stream>>>(merge_w, wmrg);
    patches_k<<<1024, 256, 0, stream>>>(x, A1);
    gemm128<0><<<dim3(32, 8, 1), 256, 0, stream>>>(A1, wmrg, nullptr, tok, nullptr, nullptr, 1024, 64, 64);

    for (int i = 0; i < 8; i++) {
        convw_k<<<12288, 256, 0, stream>>>(
            qkv_w + (size_t)i * 3072 * 1024, proj_w + (size_t)i * 1024 * 1024,
            fc1_w + (size_t)i * 4096 * 1024, fc2_w + (size_t)i * 1024 * 4096,
            wqkv, wproj, wfc1, wfc2);

        rmsnorm_k<<<4096, 256, 0, stream>>>(tok, i == 0 ? nullptr : pfc2, A1);
        gemm128<6><<<dim3(32, 24, 1), 256, 0, stream>>>(A1, wqkv, qkv_b + (size_t)i * 3072,
                                                        nullptr, nullptr, qkvb, 3072, 1024, 1024);
        vtrans_k<<<1024, 256, 0, stream>>>(qkvb, vtb);
        attn_mfma<<<512, 256, 0, stream>>>(qkvb, vtb, ob);
        gemm128<5><<<dim3(32, 8, 2), 256, 0, stream>>>(ob, wproj, proj_b + (size_t)i * 1024,
                                                       tok, pproj, nullptr, 1024, 1024, 512);
        rmsnorm_k<<<4096, 256, 0, stream>>>(tok, pproj, A2);
        gemm128<3><<<dim3(32, 32, 1), 256, 0, stream>>>(A2, wfc1, fc1_b + (size_t)i * 4096,
                                                        nullptr, nullptr, hid, 4096, 1024, 1024);
        gemm128<5><<<dim3(32, 8, 2), 256, 0, stream>>>(hid, wfc2, fc2_b + (size_t)i * 1024,
                                                       tok, pfc2, nullptr, 1024, 4096, 2048);
    }
    rmsscale_k<<<4096, 256, 0, stream>>>(tok, pfc2, scl);
    transpose_out_k<<<dim3(16, 16, 4), 256, 0, stream>>>(tok, scl, out);
}

// Round 4
// 2447.943 us; speedup vs baseline: 4.8729x; 1.0091x over previous
//
#include <hip/hip_runtime.h>
#include <hip/hip_bf16.h>
#include <cmath>

typedef __bf16 bf16_t;
typedef __bf16 bf16x4 __attribute__((ext_vector_type(4)));
typedef __bf16 bf16x8 __attribute__((ext_vector_type(8)));
typedef float f32x4 __attribute__((ext_vector_type(4)));

typedef const __attribute__((address_space(1))) void gv_t;
typedef __attribute__((address_space(3))) void sv_t;

#define GLDS16(g, l) __builtin_amdgcn_global_load_lds((gv_t*)(g), (sv_t*)(l), 16, 0, 0)

// ---------------- GEMM: C = A @ B^T (+bias)(+epilogue), 3-deep pipelined ----------------
// A: [M, K] bf16 row-major ; B: [N, K] bf16 row-major (weights [out,in])
// KS = K-chunk per blockIdx.z split (multiple of 32).
// LDS tiles XOR-swizzled (granule pos p = g ^ ((row>>1)&3)): ds_read_b128 2-way (free)
// instead of 8-way. Swizzle applied on the GLOBAL source address (global_load_lds dest
// must stay linear) and on the LDS read offset — both-sides-or-neither.
// EPI: 0 = store f32, no bias ;
//      3 = +bias, gelu, store bf16 ;
//      5 = split-K, race-free: z==0 -> Cf[row*1024+col] += v + bias ; z==1 -> Cf2[row*1024+col] = v ;
//      6 = +bias, fused 2D-RoPE on q/k cols (<2048), store bf16 (qkv gemm)
template <int EPI>
__global__ __launch_bounds__(256, 3) void gemm128(
    const bf16_t* __restrict__ A, const bf16_t* __restrict__ B,
    const float* __restrict__ bias, float* __restrict__ Cf,
    float* __restrict__ Cf2, bf16_t* __restrict__ Cb, int N, int K, int KS)
{
    __shared__ __align__(16) bf16_t As[3][128 * 32];
    __shared__ __align__(16) bf16_t Bs[3][128 * 32];
    const int tid = threadIdx.x;
    const int bm = blockIdx.x, bn = blockIdx.y, bz = blockIdx.z;
    const int wave = tid >> 6, lane = tid & 63;
    const int wr = (wave >> 1) << 6, wc = (wave & 1) << 6;
    const int lr = lane & 15;
    // swizzled read offset: granule g = lane>>4, pos = g ^ ((lr>>1)&3)  (lane-constant)
    const int koff = (((lane >> 4) ^ ((lr >> 1) & 3))) << 3;

    f32x4 acc[4][4] = {};

    const int kbeg = bz * KS;
    // staging source column pre-swizzled: colg = (tid&3) ^ ((tid>>3)&3)
    const int scol = ((tid & 3) ^ ((tid >> 3) & 3)) * 8;
    const bf16_t* gA = A + (size_t)(bm * 128 + (tid >> 2)) * K + scol + kbeg;
    const bf16_t* gB = B + (size_t)(bn * 128 + (tid >> 2)) * K + scol + kbeg;
    const bf16_t* gA2 = gA + (size_t)64 * K;
    const bf16_t* gB2 = gB + (size_t)64 * K;
    const int dst = tid * 8;
    const int nt = KS >> 5;

#define STAGE(buf, t) do { const int _k = (t) << 5;          \
        GLDS16(gA  + _k, As[buf] + dst);                     \
        GLDS16(gA2 + _k, As[buf] + dst + 2048);              \
        GLDS16(gB  + _k, Bs[buf] + dst);                     \
        GLDS16(gB2 + _k, Bs[buf] + dst + 2048); } while (0)

    STAGE(0, 0);
    if (nt > 1) STAGE(1, 1);
    int cur = 0, pre = 2;
    for (int t = 0; t < nt; ++t) {
        // wait for tile t's 4 loads (oldest); keep tile t+1's in flight
        if (t + 1 < nt) asm volatile("s_waitcnt vmcnt(4)" ::: "memory");
        else            asm volatile("s_waitcnt vmcnt(0)" ::: "memory");
        __builtin_amdgcn_s_barrier();
        if (t + 2 < nt) STAGE(pre, t + 2);

        const bf16_t* Ac = As[cur];
        const bf16_t* Bc = Bs[cur];
        bf16x8 af[4], bfr[4];
#pragma unroll
        for (int i = 0; i < 4; i++)
            af[i] = *(const bf16x8*)(Ac + (wr + i * 16 + lr) * 32 + koff);
#pragma unroll
        for (int j = 0; j < 4; j++)
            bfr[j] = *(const bf16x8*)(Bc + (wc + j * 16 + lr) * 32 + koff);
#pragma unroll
        for (int i = 0; i < 4; i++)
#pragma unroll
            for (int j = 0; j < 4; j++)
                acc[i][j] = __builtin_amdgcn_mfma_f32_16x16x32_bf16(af[i], bfr[j], acc[i][j], 0, 0, 0);

        cur = (cur == 2) ? 0 : cur + 1;
        pre = (pre == 2) ? 0 : pre + 1;
    }
#undef STAGE

    const int row0 = bm * 128 + wr + ((lane >> 4) << 2);
    const int col0 = bn * 128 + wc + lr;

    if constexpr (EPI == 6) {
        // qkv epilogue with fused 2D RoPE. Thread's 4 cols = head-rel dims
        // lr+{0,16,32,48}: pairs (lr,lr+16) rotated by pos_h, (lr+32,lr+48) by pos_w.
        float bv[4];
#pragma unroll
        for (int j = 0; j < 4; j++) bv[j] = bias[col0 + j * 16];
        const bool doRope = (col0 < 2048);
        const float invf = exp2f(-0.83048202372184056f * (float)lr);  // 10000^(-lr/16)
#pragma unroll
        for (int i = 0; i < 4; i++) {
#pragma unroll
            for (int r = 0; r < 4; r++) {
                const int row = row0 + i * 16 + r;
                float v0 = acc[i][0][r] + bv[0], v1 = acc[i][1][r] + bv[1];
                float v2 = acc[i][2][r] + bv[2], v3 = acc[i][3][r] + bv[3];
                if (doRope) {
                    const int tt = row & 1023;
                    float s0, c0, s1, c1;
                    sincosf((float)(tt >> 5) * invf, &s0, &c0);   // pos_h = t/32
                    sincosf((float)(tt & 31) * invf, &s1, &c1);   // pos_w = t%32
                    float o0 = v0 * c0 - v1 * s0, o1 = v1 * c0 + v0 * s0;
                    float o2 = v2 * c1 - v3 * s1, o3 = v3 * c1 + v2 * s1;
                    v0 = o0; v1 = o1; v2 = o2; v3 = o3;
                }
                bf16_t* cp = Cb + (size_t)row * N + col0;
                cp[0] = (bf16_t)v0; cp[16] = (bf16_t)v1;
                cp[32] = (bf16_t)v2; cp[48] = (bf16_t)v3;
            }
        }
        return;
    }

#pragma unroll
    for (int j = 0; j < 4; j++) {
        const int col = col0 + j * 16;
        float bv = 0.f;
        if constexpr (EPI == 3) bv = bias[col];
        if constexpr (EPI == 5) { if (bz == 0) bv = bias[col]; }
#pragma unroll
        for (int i = 0; i < 4; i++) {
#pragma unroll
            for (int r = 0; r < 4; r++) {
                const int row = row0 + i * 16 + r;
                float v = acc[i][j][r] + bv;
                if constexpr (EPI == 0) {
                    Cf[(size_t)row * N + col] = v;
                } else if constexpr (EPI == 5) {
                    if (bz == 0) {
                        float* dp = Cf + (size_t)row * 1024 + col;
                        *dp += v;                      // unique owner: race-free RMW
                    } else {
                        Cf2[(size_t)row * 1024 + col] = v;
                    }
                } else if constexpr (EPI == 3) {
                    float g = 0.5f * v * (1.f + tanhf(0.7978845608f * (v + 0.044715f * v * v * v)));
                    Cb[(size_t)row * N + col] = (bf16_t)g;
                }
            }
        }
    }
}

// ---------------- per-layer weight convert f32 -> bf16 (4 tensors fused) ----------------
__global__ __launch_bounds__(256) void convw_k(
    const float* __restrict__ q, const float* __restrict__ p,
    const float* __restrict__ f1, const float* __restrict__ f2,
    bf16_t* __restrict__ oq, bf16_t* __restrict__ op,
    bf16_t* __restrict__ of1, bf16_t* __restrict__ of2)
{
    int idx = blockIdx.x * 256 + threadIdx.x;   // in float4 units; 3145728 total
    const float* src; bf16_t* dst; int off;
    if (idx < 786432)       { src = q;  dst = oq;  off = idx; }
    else if (idx < 1048576) { src = p;  dst = op;  off = idx - 786432; }
    else if (idx < 2097152) { src = f1; dst = of1; off = idx - 1048576; }
    else                    { src = f2; dst = of2; off = idx - 2097152; }
    float4 v = ((const float4*)src)[off];
    bf16x4 o; o[0] = (bf16_t)v.x; o[1] = (bf16_t)v.y; o[2] = (bf16_t)v.z; o[3] = (bf16_t)v.w;
    *(bf16x4*)(dst + (size_t)off * 4) = o;
}

// ---------------- generic f32 -> bf16 convert ----------------
__global__ __launch_bounds__(256) void cvt_k(const float* __restrict__ in, bf16_t* __restrict__ out)
{
    int idx = blockIdx.x * 256 + threadIdx.x;   // float4 units
    float4 v = ((const float4*)in)[idx];
    bf16x4 o; o[0] = (bf16_t)v.x; o[1] = (bf16_t)v.y; o[2] = (bf16_t)v.z; o[3] = (bf16_t)v.w;
    *(bf16x4*)(out + (size_t)idx * 4) = o;
}

// ---------------- SpatialMerger patch gather ----------------
__global__ __launch_bounds__(256) void patches_k(const float* __restrict__ x, bf16_t* __restrict__ out)
{
    int idx = blockIdx.x * 256 + threadIdx.x;  // 262144 total
    int cc = idx & 63, l = (idx >> 6) & 1023, n = idx >> 16;
    int c = cc >> 2, kh = (cc >> 1) & 1, kw = cc & 1;
    int hf = l >> 5, wf = l & 31;
    out[idx] = (bf16_t)x[(((n * 16 + c) * 64) + hf * 2 + kh) * 64 + wf * 2 + kw];
}

// ---------------- RMSNorm (+optional partial-sum fold): tok(+p) -> tok, bf16 out ----------------
__global__ __launch_bounds__(256) void rmsnorm_k(float* __restrict__ tok,
                                                 const float* __restrict__ p,
                                                 bf16_t* __restrict__ out)
{
    int row = blockIdx.x, tid = threadIdx.x;
    float4 xv = ((const float4*)(tok + (size_t)row * 1024))[tid];
    if (p) {
        float4 pv = ((const float4*)(p + (size_t)row * 1024))[tid];
        xv.x += pv.x; xv.y += pv.y; xv.z += pv.z; xv.w += pv.w;
        ((float4*)(tok + (size_t)row * 1024))[tid] = xv;
    }
    float s = xv.x * xv.x + xv.y * xv.y + xv.z * xv.z + xv.w * xv.w;
#pragma unroll
    for (int off = 32; off > 0; off >>= 1) s += __shfl_down(s, off, 64);
    __shared__ float ws4[4];
    if ((tid & 63) == 0) ws4[tid >> 6] = s;
    __syncthreads();
    float sc = rsqrtf((ws4[0] + ws4[1] + ws4[2] + ws4[3]) * (1.f / 1024.f) + 1e-6f);
    bf16_t* o = out + (size_t)row * 1024 + tid * 4;
    bf16x4 ov;
    ov[0] = (bf16_t)(xv.x * sc); ov[1] = (bf16_t)(xv.y * sc);
    ov[2] = (bf16_t)(xv.z * sc); ov[3] = (bf16_t)(xv.w * sc);
    *(bf16x4*)o = ov;
}

// ---------------- V transpose: qkv v-section [n,t][h*64+d] -> vt [n,h,d][t] ----------------
__global__ __launch_bounds__(256) void vtrans_k(const bf16_t* __restrict__ qkv, bf16_t* __restrict__ vt)
{
    __shared__ bf16_t tile[64][72];   // 72*2=144 B rows, 16-B aligned
    const int tid = threadIdx.x, b = blockIdx.x;     // 1024 = n(4)*h(16)*tt(16)
    const int tt = b & 15, h = (b >> 4) & 15, n = b >> 8;
#pragma unroll
    for (int rr = 0; rr < 2; rr++) {
        int idx = rr * 256 + tid;
        int tr = idx >> 3, dc = (idx & 7) * 8;
        bf16x8 v = *(const bf16x8*)(qkv + (size_t)(n * 1024 + tt * 64 + tr) * 3072 + 2048 + h * 64 + dc);
        *(bf16x8*)&tile[tr][dc] = v;
    }
    __syncthreads();
#pragma unroll
    for (int rr = 0; rr < 2; rr++) {
        int idx = rr * 256 + tid;
        int d = idx >> 3, tc = (idx & 7) * 8;
        bf16x8 ov;
#pragma unroll
        for (int e = 0; e < 8; e++) ov[e] = tile[tc + e][d];
        *(bf16x8*)(vt + (size_t)((n * 16 + h) * 64 + d) * 1024 + tt * 64 + tc) = ov;
    }
}

// ---------------- MFMA flash attention ----------------
__global__ __launch_bounds__(256, 2) void attn_mfma(
    const bf16_t* __restrict__ qkv, const bf16_t* __restrict__ vt, bf16_t* __restrict__ obuf)
{
    __shared__ __align__(16) bf16_t Ks[64 * 64];     // [s][d], swizzled
    __shared__ __align__(16) bf16_t Vs[64 * 64];     // [d][s], swizzled
    __shared__ __align__(16) bf16_t Ps[4][32 * 64];  // per-wave [t][s], swizzled

    const int tid = threadIdx.x, wave = tid >> 6, lane = tid & 63;
    const int lr = lane & 15, g = lane >> 4;
    const int blk = blockIdx.x;
    const int qb = blk & 7, h = (blk >> 3) & 15, n = blk >> 7;
    const int t0 = qb * 128 + wave * 32;             // wave's first q row (within head)

    // ---- Q fragments (B-operand layout), pre-scaled by 1/sqrt(64)=0.125
    bf16x8 bq[2][2];
#pragma unroll
    for (int j = 0; j < 2; j++)
#pragma unroll
        for (int kk = 0; kk < 2; kk++) {
            bf16x8 v = *(const bf16x8*)(qkv + (size_t)(n * 1024 + t0 + j * 16 + lr) * 3072 + h * 64 + kk * 32 + g * 8);
#pragma unroll
            for (int e = 0; e < 8; e++) v[e] = (bf16_t)((float)v[e] * 0.125f);
            bq[j][kk] = v;
        }

    f32x4 o[2][4] = {};
    float m[2] = {-1e30f, -1e30f}, l[2] = {0.f, 0.f};

    const int sr = tid >> 3, pcb = tid & 7;
    const int scb = (pcb ^ (sr & 7)) * 8;            // swizzled source column (elements)
    const bf16_t* ksrc = qkv + (size_t)(n * 1024 + sr) * 3072 + 1024 + h * 64 + scb;
    const bf16_t* vsrc = vt + (size_t)((n * 16 + h) * 64 + sr) * 1024 + scb;
    bf16_t* kdst = Ks + tid * 8;
    bf16_t* vdst = Vs + tid * 8;

    for (int s0 = 0; s0 < 1024; s0 += 64) {
        __syncthreads();
        GLDS16(ksrc + (size_t)s0 * 3072, kdst);
        GLDS16(ksrc + (size_t)(s0 + 32) * 3072, kdst + 2048);
        GLDS16(vsrc + s0, vdst);
        GLDS16(vsrc + s0 + (size_t)32 * 1024, vdst + 2048);
        __syncthreads();

        // ---- S^T = K @ Q^T  (row=s: 4 blocks, col=t: 2 blocks)
        f32x4 st[4][2] = {};
#pragma unroll
        for (int kk = 0; kk < 2; kk++) {
            bf16x8 ak[4];
#pragma unroll
            for (int i = 0; i < 4; i++)
                ak[i] = *(const bf16x8*)((const char*)Ks + (i * 16 + lr) * 128 + (((kk * 4 + g) ^ (lr & 7)) * 16));
#pragma unroll
            for (int i = 0; i < 4; i++)
#pragma unroll
                for (int j = 0; j < 2; j++)
                    st[i][j] = __builtin_amdgcn_mfma_f32_16x16x32_bf16(ak[i], bq[j][kk], st[i][j], 0, 0, 0);
        }

        // ---- online softmax per t-column; write P (bf16) to per-wave LDS as [t][s]
        float al2[2];
#pragma unroll
        for (int j = 0; j < 2; j++) {
            float rm = st[0][j][0];
#pragma unroll
            for (int i = 0; i < 4; i++)
#pragma unroll
                for (int r = 0; r < 4; r++) rm = fmaxf(rm, st[i][j][r]);
            rm = fmaxf(rm, __shfl_xor(rm, 16, 64));
            rm = fmaxf(rm, __shfl_xor(rm, 32, 64));
            float mn = fmaxf(m[j], rm);
            float al = __expf(m[j] - mn);
            m[j] = mn; al2[j] = al;
            float ps = 0.f;
#pragma unroll
            for (int i = 0; i < 4; i++) {
                bf16x4 pk;
#pragma unroll
                for (int r = 0; r < 4; r++) {
                    float p = __expf(st[i][j][r] - mn);
                    bf16_t pb = (bf16_t)p;
                    pk[r] = pb;
                    ps += (float)pb;
                }
                *(bf16x4*)((char*)&Ps[wave][0] + (j * 16 + lr) * 128 +
                           (((i * 2 + (g >> 1)) ^ (lr & 7)) * 16) + (g & 1) * 8) = pk;
            }
            ps += __shfl_xor(ps, 16, 64);
            ps += __shfl_xor(ps, 32, 64);
            l[j] = l[j] * al + ps;
        }

        // ---- rescale O by alpha
#pragma unroll
        for (int ti = 0; ti < 2; ti++)
#pragma unroll
            for (int r = 0; r < 4; r++) {
                float av = __shfl(al2[ti], g * 4 + r, 64);
#pragma unroll
                for (int dj = 0; dj < 4; dj++) o[ti][dj][r] *= av;
            }

        // ---- O += P @ V
#pragma unroll
        for (int kk = 0; kk < 2; kk++) {
            bf16x8 ap[2], bv[4];
#pragma unroll
            for (int ti = 0; ti < 2; ti++)
                ap[ti] = *(const bf16x8*)((const char*)&Ps[wave][0] + (ti * 16 + lr) * 128 +
                                          (((kk * 4 + g) ^ (lr & 7)) * 16));
#pragma unroll
            for (int dj = 0; dj < 4; dj++)
                bv[dj] = *(const bf16x8*)((const char*)Vs + (dj * 16 + lr) * 128 +
                                          (((kk * 4 + g) ^ (lr & 7)) * 16));
#pragma unroll
            for (int ti = 0; ti < 2; ti++)
#pragma unroll
                for (int dj = 0; dj < 4; dj++)
                    o[ti][dj] = __builtin_amdgcn_mfma_f32_16x16x32_bf16(ap[ti], bv[dj], o[ti][dj], 0, 0, 0);
        }
    }

    // ---- epilogue: O /= l, store bf16
#pragma unroll
    for (int ti = 0; ti < 2; ti++)
#pragma unroll
        for (int r = 0; r < 4; r++) {
            float lv = __shfl(l[ti], g * 4 + r, 64);
            float inv = 1.f / lv;
            const int trow = n * 1024 + qb * 128 + wave * 32 + ti * 16 + g * 4 + r;
#pragma unroll
            for (int dj = 0; dj < 4; dj++)
                obuf[(size_t)trow * 1024 + h * 64 + dj * 16 + lr] = (bf16_t)(o[ti][dj][r] * inv);
        }
}

// ---------------- final rmsnorm scale per token (+fold fc2 partial) ----------------
__global__ __launch_bounds__(256) void rmsscale_k(float* __restrict__ tok,
                                                  const float* __restrict__ p,
                                                  float* __restrict__ scale)
{
    int row = blockIdx.x, tid = threadIdx.x;
    float4 xv = ((const float4*)(tok + (size_t)row * 1024))[tid];
    if (p) {
        float4 pv = ((const float4*)(p + (size_t)row * 1024))[tid];
        xv.x += pv.x; xv.y += pv.y; xv.z += pv.z; xv.w += pv.w;
        ((float4*)(tok + (size_t)row * 1024))[tid] = xv;
    }
    float s = xv.x * xv.x + xv.y * xv.y + xv.z * xv.z + xv.w * xv.w;
#pragma unroll
    for (int off = 32; off > 0; off >>= 1) s += __shfl_down(s, off, 64);
    __shared__ float ws4[4];
    if ((tid & 63) == 0) ws4[tid >> 6] = s;
    __syncthreads();
    if (tid == 0)
        scale[row] = rsqrtf((ws4[0] + ws4[1] + ws4[2] + ws4[3]) * (1.f / 1024.f) + 1e-6f);
}

// ---------------- scale + transpose: out f32 [n][d][t] = tok[n][t][d]*scale[n,t] ----------------
__global__ __launch_bounds__(256) void transpose_out_k(const float* __restrict__ tok,
                                                       const float* __restrict__ scale,
                                                       float* __restrict__ out)
{
    __shared__ float tile[64][65];
    const int tid = threadIdx.x;
    const int tt = blockIdx.x * 64, dd = blockIdx.y * 64, n = blockIdx.z;
#pragma unroll
    for (int rb = 0; rb < 4; rb++) {
        int tl = rb * 16 + (tid >> 4);
        int cl = (tid & 15) * 4;
        float4 v = *(const float4*)(tok + (size_t)(n * 1024 + tt + tl) * 1024 + dd + cl);
        float sc = scale[n * 1024 + tt + tl];
        tile[cl + 0][tl] = v.x * sc;
        tile[cl + 1][tl] = v.y * sc;
        tile[cl + 2][tl] = v.z * sc;
        tile[cl + 3][tl] = v.w * sc;
    }
    __syncthreads();
#pragma unroll
    for (int rb = 0; rb < 4; rb++) {
        int dl = rb * 16 + (tid >> 4);
        int tl = (tid & 15) * 4;
        float4 v = make_float4(tile[dl][tl + 0], tile[dl][tl + 1], tile[dl][tl + 2], tile[dl][tl + 3]);
        *(float4*)(out + (size_t)n * 1024 * 1024 + (size_t)(dd + dl) * 1024 + tt + tl) = v;
    }
}

extern "C" void kernel_launch(void* const* d_in, const int* in_sizes, int n_in,
                              void* d_out, int out_size, void* d_ws, size_t ws_size,
                              hipStream_t stream)
{
    const float* x       = (const float*)d_in[0];
    const float* merge_w = (const float*)d_in[1];
    const float* qkv_w   = (const float*)d_in[2];
    const float* qkv_b   = (const float*)d_in[3];
    const float* proj_w  = (const float*)d_in[4];
    const float* proj_b  = (const float*)d_in[5];
    const float* fc1_w   = (const float*)d_in[6];
    const float* fc1_b   = (const float*)d_in[7];
    const float* fc2_w   = (const float*)d_in[8];
    const float* fc2_b   = (const float*)d_in[9];
    float* out = (float*)d_out;

    // Workspace (~91 MB), aliased by liveness:
    //  [0,16)   tok f32
    //  [16,32)  pfc2 f32 (fc2 z1 partial; consumed by next-layer rmsnorm1)
    //           also vtb bf16 [16,24) (vtrans->attn) and A2 bf16 [16,24) (rmsnorm2->fc1)
    //  [24,32)  ob bf16 (attn out -> proj A)
    //  [32,40)  A1 bf16 (rmsnorm1 out -> qkv A; also patches for merge)
    //  [40,64)  qkvb bf16 (qkv out; dead after attn)
    //           also pproj f32 [40,56) (proj z1 partial -> rmsnorm2)
    //  [32,64)  hid bf16 (fc1 out -> fc2 A; overwrites A1/pproj after both dead)
    //  [64,~89.2) weights bf16 ; [90) wmrg ; [91) scl
    char* ws = (char*)d_ws;
    float*  tok   = (float*)ws;
    float*  pfc2  = (float*)(ws + (16u << 20));
    bf16_t* vtb   = (bf16_t*)(ws + (16u << 20));
    bf16_t* A2    = (bf16_t*)(ws + (16u << 20));
    bf16_t* ob    = (bf16_t*)(ws + (24u << 20));
    bf16_t* A1    = (bf16_t*)(ws + (32u << 20));
    bf16_t* qkvb  = (bf16_t*)(ws + (40u << 20));
    float*  pproj = (float*)(ws + (40u << 20));
    bf16_t* hid   = (bf16_t*)(ws + (32u << 20));
    bf16_t* wqkv  = (bf16_t*)(ws + (64u << 20));
    bf16_t* wproj = wqkv + (size_t)3072 * 1024;
    bf16_t* wfc1  = wproj + (size_t)1024 * 1024;
    bf16_t* wfc2  = wfc1 + (size_t)4096 * 1024;
    bf16_t* wmrg  = (bf16_t*)(ws + (90u << 20));
    float*  scl   = (float*)(ws + (91u << 20));

    cvt_k<<<64, 256, 0, stream>>>(merge_w, wmrg);
    patches_k<<<1024, 256, 0, stream>>>(x, A1);
    gemm128<0><<<dim3(32, 8, 1), 256, 0, stream>>>(A1, wmrg, nullptr, tok, nullptr, nullptr, 1024, 64, 64);

    for (int i = 0; i < 8; i++) {
        convw_k<<<12288, 256, 0, stream>>>(
            qkv_w + (size_t)i * 3072 * 1024, proj_w + (size_t)i * 1024 * 1024,
            fc1_w + (size_t)i * 4096 * 1024, fc2_w + (size_t)i * 1024 * 4096,
            wqkv, wproj, wfc1, wfc2);

        rmsnorm_k<<<4096, 256, 0, stream>>>(tok, i == 0 ? nullptr : pfc2, A1);
        gemm128<6><<<dim3(32, 24, 1), 256, 0, stream>>>(A1, wqkv, qkv_b + (size_t)i * 3072,
                                                        nullptr, nullptr, qkvb, 3072, 1024, 1024);
        vtrans_k<<<1024, 256, 0, stream>>>(qkvb, vtb);
        attn_mfma<<<512, 256, 0, stream>>>(qkvb, vtb, ob);
        gemm128<5><<<dim3(32, 8, 2), 256, 0, stream>>>(ob, wproj, proj_b + (size_t)i * 1024,
                                                       tok, pproj, nullptr, 1024, 1024, 512);
        rmsnorm_k<<<4096, 256, 0, stream>>>(tok, pproj, A2);
        gemm128<3><<<dim3(32, 32, 1), 256, 0, stream>>>(A2, wfc1, fc1_b + (size_t)i * 4096,
                                                        nullptr, nullptr, hid, 4096, 1024, 1024);
        gemm128<5><<<dim3(32, 8, 2), 256, 0, stream>>>(hid, wfc2, fc2_b + (size_t)i * 1024,
                                                       tok, pfc2, nullptr, 1024, 4096, 2048);
    }
    rmsscale_k<<<4096, 256, 0, stream>>>(tok, pfc2, scl);
    transpose_out_k<<<dim3(16, 16, 4), 256, 0, stream>>>(tok, scl, out);
}